// Round 2
// baseline (6283.414 us; speedup 1.0000x reference)
//
#include <hip/hip_runtime.h>

#define D 64

// ---------------------------------------------------------------------------
// init: emb = concat(user_emb, item_emb); acc = emb; embn = 0
// float4 grid-stride over N*D elements
// ---------------------------------------------------------------------------
__global__ void lgcn_init(const float* __restrict__ ue, const float* __restrict__ ie,
                          float* __restrict__ emb, float* __restrict__ acc,
                          float* __restrict__ embn,
                          int n_user_vec4, int n_total_vec4) {
    int stride = gridDim.x * blockDim.x;
    for (int i = blockIdx.x * blockDim.x + threadIdx.x; i < n_total_vec4; i += stride) {
        float4 v;
        if (i < n_user_vec4) v = ((const float4*)ue)[i];
        else                 v = ((const float4*)ie)[i - n_user_vec4];
        ((float4*)emb)[i]  = v;
        ((float4*)acc)[i]  = v;
        ((float4*)embn)[i] = make_float4(0.f, 0.f, 0.f, 0.f);
    }
}

// ---------------------------------------------------------------------------
// scatter: embn[rows[e]] += vals[e] * emb[cols[e]]
// 16 threads per edge, float4 each, 4 f32 atomics each
// ---------------------------------------------------------------------------
__global__ void lgcn_scatter(const float* __restrict__ vals,
                             const int*  __restrict__ rows,
                             const int*  __restrict__ cols,
                             const float* __restrict__ emb,
                             float* __restrict__ embn,
                             int E) {
    int gid  = blockIdx.x * blockDim.x + threadIdx.x;
    int e    = gid >> 4;
    int part = gid & 15;
    if (e >= E) return;
    int   r = rows[e];
    int   c = cols[e];
    float v = vals[e];
    float4 x = ((const float4*)(emb + (long long)c * D))[part];
    float* dst = embn + (long long)r * D + part * 4;
    atomicAdd(dst + 0, v * x.x);
    atomicAdd(dst + 1, v * x.y);
    atomicAdd(dst + 2, v * x.z);
    atomicAdd(dst + 3, v * x.w);
}

// ---------------------------------------------------------------------------
// update: per node row (one 64-lane wave per row):
//   s   = sum_d (old - new + eps)^2       (wave shuffle reduce)
//   dn  = log1p(sqrt(s)); da = 1 + dn
//   out = (old + dn*new) / da
//   emb = out; acc += out; embn = 0 (ready for next layer)
// ---------------------------------------------------------------------------
__global__ void lgcn_update(float* __restrict__ emb, float* __restrict__ embn,
                            float* __restrict__ acc, int N) {
    int gid  = blockIdx.x * blockDim.x + threadIdx.x;
    int row  = gid >> 6;
    int lane = gid & 63;
    if (row >= N) return;
    long long idx = (long long)row * D + lane;
    float o  = emb[idx];
    float nv = embn[idx];
    float d  = o - nv + 1e-6f;
    float s  = d * d;
    #pragma unroll
    for (int off = 32; off; off >>= 1) s += __shfl_xor(s, off);
    float os = sqrtf(s);
    float dn = log1pf(os);            // ALPHA = 1
    float da = 1.0f + dn;
    float out = (o + dn * nv) / da;   // score_old*o + score_new*nv
    emb[idx]  = out;
    acc[idx] += out;
    embn[idx] = 0.0f;
}

// ---------------------------------------------------------------------------
// gather: out rows = acc[user_id]/4 then acc[n_users + item_id]/4
// one 64-lane wave per output row
// ---------------------------------------------------------------------------
__global__ void lgcn_gather(const float* __restrict__ acc,
                            const int* __restrict__ uid,
                            const int* __restrict__ iid,
                            float* __restrict__ out,
                            int n_q, int n_users) {
    int gid  = blockIdx.x * blockDim.x + threadIdx.x;
    int row  = gid >> 6;
    int lane = gid & 63;
    if (row >= 2 * n_q) return;
    int src = (row < n_q) ? uid[row] : (n_users + iid[row - n_q]);
    out[(long long)row * D + lane] = acc[(long long)src * D + lane] * 0.25f;
}

extern "C" void kernel_launch(void* const* d_in, const int* in_sizes, int n_in,
                              void* d_out, int out_size, void* d_ws, size_t ws_size,
                              hipStream_t stream) {
    const float* ue   = (const float*)d_in[0];
    const float* ie   = (const float*)d_in[1];
    const float* vals = (const float*)d_in[2];
    const int*   rows = (const int*)d_in[3];
    const int*   cols = (const int*)d_in[4];
    const int*   uid  = (const int*)d_in[5];
    const int*   iid  = (const int*)d_in[6];
    float*       out  = (float*)d_out;

    const int nU = in_sizes[0] / D;
    const int nI = in_sizes[1] / D;
    const int N  = nU + nI;
    const int E  = in_sizes[2];
    const int nQ = in_sizes[5];

    float* emb  = (float*)d_ws;
    float* embn = emb  + (size_t)N * D;
    float* acc  = embn + (size_t)N * D;

    const int totalVec4 = N * D / 4;
    lgcn_init<<<2048, 256, 0, stream>>>(ue, ie, emb, acc, embn,
                                        in_sizes[0] / 4, totalVec4);

    const int scatterThreads = E * 16;
    const int scatterBlocks  = (scatterThreads + 255) / 256;
    const int updateBlocks   = (N + 3) / 4;   // 4 rows (waves) per 256-thr block

    for (int layer = 0; layer < 3; ++layer) {
        lgcn_scatter<<<scatterBlocks, 256, 0, stream>>>(vals, rows, cols, emb, embn, E);
        lgcn_update<<<updateBlocks, 256, 0, stream>>>(emb, embn, acc, N);
    }

    const int gatherBlocks = (2 * nQ * 64 + 255) / 256;
    lgcn_gather<<<gatherBlocks, 256, 0, stream>>>(acc, uid, iid, out, nQ, nU);
}

// Round 3
// 841.399 us; speedup vs baseline: 7.4678x; 7.4678x over previous
//
#include <hip/hip_runtime.h>

#define D 64

// ---------------------------------------------------------------------------
// zero an int buffer (ws is poisoned 0xAA each call)
// ---------------------------------------------------------------------------
__global__ void k_zero_int(int* __restrict__ p, int n) {
    int stride = gridDim.x * blockDim.x;
    for (int i = blockIdx.x * blockDim.x + threadIdx.x; i < n; i += stride) p[i] = 0;
}

// ---------------------------------------------------------------------------
// emb = concat(user_emb, item_emb), float4 grid-stride
// ---------------------------------------------------------------------------
__global__ void k_init(const float4* __restrict__ ue, const float4* __restrict__ ie,
                       float4* __restrict__ emb, int nUser4, int nTot4) {
    int stride = gridDim.x * blockDim.x;
    for (int i = blockIdx.x * blockDim.x + threadIdx.x; i < nTot4; i += stride)
        emb[i] = (i < nUser4) ? ue[i] : ie[i - nUser4];
}

// ---------------------------------------------------------------------------
// CSR build step 1: per-row edge counts
// ---------------------------------------------------------------------------
__global__ void k_hist(const int* __restrict__ rows, int* __restrict__ counts, int E) {
    int e = blockIdx.x * blockDim.x + threadIdx.x;
    if (e < E) atomicAdd(&counts[rows[e]], 1);
}

// ---------------------------------------------------------------------------
// CSR build step 2a: per-1024-chunk partial sums (256 thr, 4 contiguous each)
// ---------------------------------------------------------------------------
__global__ void k_scan_partial(const int* __restrict__ counts, int* __restrict__ partials, int N) {
    __shared__ int s[256];
    int t = threadIdx.x;
    int base = blockIdx.x * 1024 + t * 4;
    int sum = 0;
    #pragma unroll
    for (int k = 0; k < 4; ++k) { int i = base + k; if (i < N) sum += counts[i]; }
    s[t] = sum; __syncthreads();
    for (int off = 128; off; off >>= 1) { if (t < off) s[t] += s[t + off]; __syncthreads(); }
    if (t == 0) partials[blockIdx.x] = s[0];
}

// ---------------------------------------------------------------------------
// CSR build step 2b: exclusive scan of <=256 partials; also row_start[N]=E
// ---------------------------------------------------------------------------
__global__ void k_scan_block(const int* __restrict__ partials, int* __restrict__ blockoff,
                             int NB, int* __restrict__ row_start, int N, int E) {
    __shared__ int s[256];
    int t = threadIdx.x;
    int x = (t < NB) ? partials[t] : 0;
    s[t] = x; __syncthreads();
    for (int off = 1; off < 256; off <<= 1) {
        int v = (t >= off) ? s[t - off] : 0; __syncthreads();
        s[t] += v; __syncthreads();
    }
    if (t < NB) blockoff[t] = s[t] - x;   // exclusive
    if (t == 0) row_start[N] = E;
}

// ---------------------------------------------------------------------------
// CSR build step 2c: expand to row_start / cursor
// ---------------------------------------------------------------------------
__global__ void k_scan_expand(const int* __restrict__ counts, const int* __restrict__ blockoff,
                              int* __restrict__ row_start, int* __restrict__ cursor, int N) {
    __shared__ int s[256];
    int t = threadIdx.x, b = blockIdx.x;
    int base = b * 1024 + t * 4;
    int c0 = (base + 0 < N) ? counts[base + 0] : 0;
    int c1 = (base + 1 < N) ? counts[base + 1] : 0;
    int c2 = (base + 2 < N) ? counts[base + 2] : 0;
    int c3 = (base + 3 < N) ? counts[base + 3] : 0;
    int mySum = c0 + c1 + c2 + c3;
    s[t] = mySum; __syncthreads();
    for (int off = 1; off < 256; off <<= 1) {
        int v = (t >= off) ? s[t - off] : 0; __syncthreads();
        s[t] += v; __syncthreads();
    }
    int run = blockoff[b] + s[t] - mySum;
    if (base + 0 < N) { row_start[base + 0] = run; cursor[base + 0] = run; run += c0; }
    if (base + 1 < N) { row_start[base + 1] = run; cursor[base + 1] = run; run += c1; }
    if (base + 2 < N) { row_start[base + 2] = run; cursor[base + 2] = run; run += c2; }
    if (base + 3 < N) { row_start[base + 3] = run; cursor[base + 3] = run; run += c3; }
}

// ---------------------------------------------------------------------------
// CSR build step 3: scatter (col,val) into CSR slots via atomic tickets
// (within-row order arbitrary -> only f32 rounding nondeterminism)
// ---------------------------------------------------------------------------
__global__ void k_fill(const int* __restrict__ rows, const int* __restrict__ cols,
                       const float* __restrict__ vals, int* __restrict__ cursor,
                       int* __restrict__ csr_col, float* __restrict__ csr_val, int E) {
    int e = blockIdx.x * blockDim.x + threadIdx.x;
    if (e >= E) return;
    int p = atomicAdd(&cursor[rows[e]], 1);
    csr_col[p] = cols[e];
    csr_val[p] = vals[e];
}

// ---------------------------------------------------------------------------
// fused SpMM + growth-score update. One 64-lane wave per row, lane = dim.
// Batch-load up to 64 (col,val) pairs coalesced, shfl-broadcast each.
// ---------------------------------------------------------------------------
__global__ void k_spmm(const float* __restrict__ emb_in, float* __restrict__ emb_out,
                       const int* __restrict__ csr_col, const float* __restrict__ csr_val,
                       const int* __restrict__ row_start, int N) {
    int gid  = blockIdx.x * blockDim.x + threadIdx.x;
    int row  = gid >> 6;
    int lane = gid & 63;
    if (row >= N) return;
    int start = row_start[row], end = row_start[row + 1];
    float acc = 0.f;
    int j = start;
    while (j < end) {
        int take = end - j; if (take > 64) take = 64;
        int   cl = (lane < take) ? csr_col[j + lane] : 0;
        float vl = (lane < take) ? csr_val[j + lane] : 0.f;
        for (int k = 0; k < take; ++k) {
            int   c = __shfl(cl, k);
            float v = __shfl(vl, k);
            acc += v * emb_in[(size_t)c * D + lane];
        }
        j += take;
    }
    // growth-score blend (XiangDuiOuSi): out = (old + dn*new) / (1+dn)
    float o = emb_in[(size_t)row * D + lane];
    float d = o - acc + 1e-6f;
    float s = d * d;
    #pragma unroll
    for (int off = 32; off; off >>= 1) s += __shfl_xor(s, off);
    float dn = log1pf(sqrtf(s));
    emb_out[(size_t)row * D + lane] = (o + dn * acc) / (1.f + dn);
}

// ---------------------------------------------------------------------------
// gather snapshot rows for the 2048 queries; optionally add prev, scale.
// ---------------------------------------------------------------------------
__global__ void k_gather(const float* __restrict__ emb, const float* __restrict__ prev,
                         float* __restrict__ dst, const int* __restrict__ uid,
                         const int* __restrict__ iid, int nQ, int nU, float scale) {
    int gid  = blockIdx.x * blockDim.x + threadIdx.x;
    int r    = gid >> 6;
    int lane = gid & 63;
    if (r >= 2 * nQ) return;
    int src = (r < nQ) ? uid[r] : nU + iid[r - nQ];
    float v = emb[(size_t)src * D + lane];
    if (prev) v += prev[(size_t)r * D + lane];
    dst[(size_t)r * D + lane] = v * scale;
}

extern "C" void kernel_launch(void* const* d_in, const int* in_sizes, int n_in,
                              void* d_out, int out_size, void* d_ws, size_t ws_size,
                              hipStream_t stream) {
    const float* ue   = (const float*)d_in[0];
    const float* ie   = (const float*)d_in[1];
    const float* vals = (const float*)d_in[2];
    const int*   rows = (const int*)d_in[3];
    const int*   cols = (const int*)d_in[4];
    const int*   uid  = (const int*)d_in[5];
    const int*   iid  = (const int*)d_in[6];
    float*       out  = (float*)d_out;

    const int nU = in_sizes[0] / D;
    const int nI = in_sizes[1] / D;
    const int N  = nU + nI;
    const int E  = in_sizes[2];
    const int nQ = in_sizes[5];
    const int NB = (N + 1023) / 1024;           // scan chunks (147 for N=150k)

    // ---- workspace layout (16B aligned) ----
    char* p = (char*)d_ws;
    auto alloc = [&](size_t bytes) { char* r = p; p += (bytes + 15) & ~(size_t)15; return r; };
    float* emb_a     = (float*)alloc((size_t)N * D * 4);
    float* emb_b     = (float*)alloc((size_t)N * D * 4);
    int*   csr_col   = (int*)  alloc((size_t)E * 4);
    float* csr_val   = (float*)alloc((size_t)E * 4);
    int*   row_start = (int*)  alloc((size_t)(N + 1) * 4);
    int*   cursor    = (int*)  alloc((size_t)N * 4);
    int*   counts    = (int*)  alloc((size_t)N * 4);
    int*   partials  = (int*)  alloc((size_t)NB * 4);
    int*   blockoff  = (int*)  alloc((size_t)NB * 4);
    float* outacc    = (float*)alloc((size_t)2 * nQ * D * 4);

    const int eBlocks    = (E + 255) / 256;
    const int spmmBlocks = (N * 64 + 255) / 256;
    const int gatBlocks  = (2 * nQ * 64 + 255) / 256;

    // ---- init + CSR build (once; reused by all 3 layers) ----
    k_zero_int<<<256, 256, 0, stream>>>(counts, N);
    k_init<<<2048, 256, 0, stream>>>((const float4*)ue, (const float4*)ie,
                                     (float4*)emb_a, in_sizes[0] / 4, N * D / 4);
    k_hist<<<eBlocks, 256, 0, stream>>>(rows, counts, E);
    k_scan_partial<<<NB, 256, 0, stream>>>(counts, partials, N);
    k_scan_block<<<1, 256, 0, stream>>>(partials, blockoff, NB, row_start, N, E);
    k_scan_expand<<<NB, 256, 0, stream>>>(counts, blockoff, row_start, cursor, N);
    k_fill<<<eBlocks, 256, 0, stream>>>(rows, cols, vals, cursor, csr_col, csr_val, E);

    // ---- snapshot 0 ----
    k_gather<<<gatBlocks, 256, 0, stream>>>(emb_a, nullptr, outacc, uid, iid, nQ, nU, 1.0f);

    // ---- 3 fused layers, ping-pong ----
    k_spmm<<<spmmBlocks, 256, 0, stream>>>(emb_a, emb_b, csr_col, csr_val, row_start, N);
    k_gather<<<gatBlocks, 256, 0, stream>>>(emb_b, outacc, outacc, uid, iid, nQ, nU, 1.0f);

    k_spmm<<<spmmBlocks, 256, 0, stream>>>(emb_b, emb_a, csr_col, csr_val, row_start, N);
    k_gather<<<gatBlocks, 256, 0, stream>>>(emb_a, outacc, outacc, uid, iid, nQ, nU, 1.0f);

    k_spmm<<<spmmBlocks, 256, 0, stream>>>(emb_a, emb_b, csr_col, csr_val, row_start, N);
    k_gather<<<gatBlocks, 256, 0, stream>>>(emb_b, outacc, out, uid, iid, nQ, nU, 0.25f);
}

// Round 4
// 807.679 us; speedup vs baseline: 7.7796x; 1.0417x over previous
//
#include <hip/hip_runtime.h>

#define D 64

// f32 -> bf16 round-to-nearest-even (finite values only)
__device__ inline unsigned short f2bf(float f) {
    unsigned u = __float_as_uint(f);
    u += 0x7FFF + ((u >> 16) & 1);
    return (unsigned short)(u >> 16);
}
__device__ inline float bf2f(unsigned short h) {
    return __uint_as_float((unsigned)h << 16);
}

// ---------------------------------------------------------------------------
__global__ void k_zero_int(int* __restrict__ p, int n) {
    int stride = gridDim.x * blockDim.x;
    for (int i = blockIdx.x * blockDim.x + threadIdx.x; i < n; i += stride) p[i] = 0;
}

// ---------------------------------------------------------------------------
// master = concat(user_emb, item_emb); m16 = bf16(master)
// ---------------------------------------------------------------------------
__global__ void k_init(const float4* __restrict__ ue, const float4* __restrict__ ie,
                       float4* __restrict__ master, ushort4* __restrict__ m16,
                       int nUser4, int nTot4) {
    int stride = gridDim.x * blockDim.x;
    for (int i = blockIdx.x * blockDim.x + threadIdx.x; i < nTot4; i += stride) {
        float4 v = (i < nUser4) ? ue[i] : ie[i - nUser4];
        master[i] = v;
        ushort4 h;
        h.x = f2bf(v.x); h.y = f2bf(v.y); h.z = f2bf(v.z); h.w = f2bf(v.w);
        m16[i] = h;
    }
}

// ---------------------------------------------------------------------------
// CSR build step 1: per-row edge counts
// ---------------------------------------------------------------------------
__global__ void k_hist(const int* __restrict__ rows, int* __restrict__ counts, int E) {
    int e = blockIdx.x * blockDim.x + threadIdx.x;
    if (e < E) atomicAdd(&counts[rows[e]], 1);
}

// ---------------------------------------------------------------------------
// CSR build step 2a: per-1024-chunk partial sums
// ---------------------------------------------------------------------------
__global__ void k_scan_partial(const int* __restrict__ counts, int* __restrict__ partials, int N) {
    __shared__ int s[256];
    int t = threadIdx.x;
    int base = blockIdx.x * 1024 + t * 4;
    int sum = 0;
    #pragma unroll
    for (int k = 0; k < 4; ++k) { int i = base + k; if (i < N) sum += counts[i]; }
    s[t] = sum; __syncthreads();
    for (int off = 128; off; off >>= 1) { if (t < off) s[t] += s[t + off]; __syncthreads(); }
    if (t == 0) partials[blockIdx.x] = s[0];
}

// ---------------------------------------------------------------------------
// CSR build step 2b: exclusive scan of <=256 partials; also row_start[N]=E
// ---------------------------------------------------------------------------
__global__ void k_scan_block(const int* __restrict__ partials, int* __restrict__ blockoff,
                             int NB, int* __restrict__ row_start, int N, int E) {
    __shared__ int s[256];
    int t = threadIdx.x;
    int x = (t < NB) ? partials[t] : 0;
    s[t] = x; __syncthreads();
    for (int off = 1; off < 256; off <<= 1) {
        int v = (t >= off) ? s[t - off] : 0; __syncthreads();
        s[t] += v; __syncthreads();
    }
    if (t < NB) blockoff[t] = s[t] - x;   // exclusive
    if (t == 0) row_start[N] = E;
}

// ---------------------------------------------------------------------------
// CSR build step 2c: expand to row_start / cursor
// ---------------------------------------------------------------------------
__global__ void k_scan_expand(const int* __restrict__ counts, const int* __restrict__ blockoff,
                              int* __restrict__ row_start, int* __restrict__ cursor, int N) {
    __shared__ int s[256];
    int t = threadIdx.x, b = blockIdx.x;
    int base = b * 1024 + t * 4;
    int c0 = (base + 0 < N) ? counts[base + 0] : 0;
    int c1 = (base + 1 < N) ? counts[base + 1] : 0;
    int c2 = (base + 2 < N) ? counts[base + 2] : 0;
    int c3 = (base + 3 < N) ? counts[base + 3] : 0;
    int mySum = c0 + c1 + c2 + c3;
    s[t] = mySum; __syncthreads();
    for (int off = 1; off < 256; off <<= 1) {
        int v = (t >= off) ? s[t - off] : 0; __syncthreads();
        s[t] += v; __syncthreads();
    }
    int run = blockoff[b] + s[t] - mySum;
    if (base + 0 < N) { row_start[base + 0] = run; cursor[base + 0] = run; run += c0; }
    if (base + 1 < N) { row_start[base + 1] = run; cursor[base + 1] = run; run += c1; }
    if (base + 2 < N) { row_start[base + 2] = run; cursor[base + 2] = run; run += c2; }
    if (base + 3 < N) { row_start[base + 3] = run; cursor[base + 3] = run; run += c3; }
}

// ---------------------------------------------------------------------------
// CSR build step 3: scatter (col,val) pairs into CSR slots, row range [lo,hi)
// int2 single 8B store halves dirty lines; range passes shrink the scatter
// window to ~L2 size so lines survive until fully written.
// ---------------------------------------------------------------------------
__global__ void k_fill(const int* __restrict__ rows, const int* __restrict__ cols,
                       const float* __restrict__ vals, int* __restrict__ cursor,
                       int2* __restrict__ csr_pair, int E, int lo, int hi) {
    int e = blockIdx.x * blockDim.x + threadIdx.x;
    if (e >= E) return;
    int r = rows[e];
    if (r < lo || r >= hi) return;
    int p = atomicAdd(&cursor[r], 1);
    int2 pr;
    pr.x = cols[e];
    pr.y = __float_as_int(vals[e]);
    csr_pair[p] = pr;
}

// ---------------------------------------------------------------------------
// fused SpMM + growth-score update. One 64-lane wave per row, lane = dim.
// Gather source is the bf16 mirror (halves gather bytes); blend old value and
// output stay f32 (in-place master update is safe: only own wave reads it).
// ---------------------------------------------------------------------------
__global__ void k_spmm(float* __restrict__ master,
                       const ushort* __restrict__ m16_in, ushort* __restrict__ m16_out,
                       const int2* __restrict__ csr_pair,
                       const int* __restrict__ row_start, int N) {
    int gid  = blockIdx.x * blockDim.x + threadIdx.x;
    int row  = gid >> 6;
    int lane = gid & 63;
    if (row >= N) return;
    int start = row_start[row], end = row_start[row + 1];
    float o = master[(size_t)row * D + lane];
    float acc = 0.f;
    for (int j = start; j < end; j += 64) {
        int take = end - j; if (take > 64) take = 64;
        int2 pr = (lane < take) ? csr_pair[j + lane] : make_int2(0, 0);
        for (int k = 0; k < take; ++k) {
            int   c = __shfl(pr.x, k);
            float v = __int_as_float(__shfl(pr.y, k));
            acc += v * bf2f(m16_in[(size_t)c * D + lane]);
        }
    }
    float d = o - acc + 1e-6f;
    float s = d * d;
    #pragma unroll
    for (int off = 32; off; off >>= 1) s += __shfl_xor(s, off);
    float dn = log1pf(sqrtf(s));
    float out = (o + dn * acc) / (1.f + dn);
    master[(size_t)row * D + lane]  = out;
    m16_out[(size_t)row * D + lane] = f2bf(out);
}

// ---------------------------------------------------------------------------
// gather snapshot rows for the queries; optionally add prev, scale.
// ---------------------------------------------------------------------------
__global__ void k_gather(const float* __restrict__ emb, const float* __restrict__ prev,
                         float* __restrict__ dst, const int* __restrict__ uid,
                         const int* __restrict__ iid, int nQ, int nU, float scale) {
    int gid  = blockIdx.x * blockDim.x + threadIdx.x;
    int r    = gid >> 6;
    int lane = gid & 63;
    if (r >= 2 * nQ) return;
    int src = (r < nQ) ? uid[r] : nU + iid[r - nQ];
    float v = emb[(size_t)src * D + lane];
    if (prev) v += prev[(size_t)r * D + lane];
    dst[(size_t)r * D + lane] = v * scale;
}

extern "C" void kernel_launch(void* const* d_in, const int* in_sizes, int n_in,
                              void* d_out, int out_size, void* d_ws, size_t ws_size,
                              hipStream_t stream) {
    const float* ue   = (const float*)d_in[0];
    const float* ie   = (const float*)d_in[1];
    const float* vals = (const float*)d_in[2];
    const int*   rows = (const int*)d_in[3];
    const int*   cols = (const int*)d_in[4];
    const int*   uid  = (const int*)d_in[5];
    const int*   iid  = (const int*)d_in[6];
    float*       out  = (float*)d_out;

    const int nU = in_sizes[0] / D;
    const int nI = in_sizes[1] / D;
    const int N  = nU + nI;
    const int E  = in_sizes[2];
    const int nQ = in_sizes[5];
    const int NB = (N + 1023) / 1024;

    // ---- workspace layout (16B aligned), ~98 MB total ----
    char* p = (char*)d_ws;
    auto alloc = [&](size_t bytes) { char* r = p; p += (bytes + 15) & ~(size_t)15; return r; };
    float*  master    = (float*) alloc((size_t)N * D * 4);
    ushort* m16a      = (ushort*)alloc((size_t)N * D * 2);
    ushort* m16b      = (ushort*)alloc((size_t)N * D * 2);
    int2*   csr_pair  = (int2*)  alloc((size_t)E * 8);
    int*    row_start = (int*)   alloc((size_t)(N + 1) * 4);
    int*    cursor    = (int*)   alloc((size_t)N * 4);
    int*    counts    = (int*)   alloc((size_t)N * 4);
    int*    partials  = (int*)   alloc((size_t)NB * 4);
    int*    blockoff  = (int*)   alloc((size_t)NB * 4);
    float*  outacc    = (float*) alloc((size_t)2 * nQ * D * 4);

    const int eBlocks    = (E + 255) / 256;
    const int spmmBlocks = (N * 64 + 255) / 256;
    const int gatBlocks  = (2 * nQ * 64 + 255) / 256;

    // ---- init + CSR build (reused by all 3 layers) ----
    k_zero_int<<<256, 256, 0, stream>>>(counts, N);
    k_init<<<2048, 256, 0, stream>>>((const float4*)ue, (const float4*)ie,
                                     (float4*)master, (ushort4*)m16a,
                                     in_sizes[0] / 4, N * D / 4);
    k_hist<<<eBlocks, 256, 0, stream>>>(rows, counts, E);
    k_scan_partial<<<NB, 256, 0, stream>>>(counts, partials, N);
    k_scan_block<<<1, 256, 0, stream>>>(partials, blockoff, NB, row_start, N, E);
    k_scan_expand<<<NB, 256, 0, stream>>>(counts, blockoff, row_start, cursor, N);
    // 4 row-range passes: scatter window ~E/4*8B = 4.8 MB each
    {
        int q = (N + 3) / 4;
        for (int ppass = 0; ppass < 4; ++ppass) {
            int lo = ppass * q;
            int hi = (ppass == 3) ? N : (lo + q);
            k_fill<<<eBlocks, 256, 0, stream>>>(rows, cols, vals, cursor, csr_pair, E, lo, hi);
        }
    }

    // ---- snapshot 0 ----
    k_gather<<<gatBlocks, 256, 0, stream>>>(master, nullptr, outacc, uid, iid, nQ, nU, 1.0f);

    // ---- 3 fused layers (master updated in place; bf16 mirror ping-pongs) ----
    k_spmm<<<spmmBlocks, 256, 0, stream>>>(master, m16a, m16b, csr_pair, row_start, N);
    k_gather<<<gatBlocks, 256, 0, stream>>>(master, outacc, outacc, uid, iid, nQ, nU, 1.0f);

    k_spmm<<<spmmBlocks, 256, 0, stream>>>(master, m16b, m16a, csr_pair, row_start, N);
    k_gather<<<gatBlocks, 256, 0, stream>>>(master, outacc, outacc, uid, iid, nQ, nU, 1.0f);

    k_spmm<<<spmmBlocks, 256, 0, stream>>>(master, m16a, m16b, csr_pair, row_start, N);
    k_gather<<<gatBlocks, 256, 0, stream>>>(master, outacc, out, uid, iid, nQ, nU, 0.25f);
}

// Round 5
// 682.650 us; speedup vs baseline: 9.2044x; 1.1832x over previous
//
#include <hip/hip_runtime.h>

#define D 64
#define BSH 4                       // rows per bucket = 16
#define BMASK ((1 << BSH) - 1)

// f32 -> bf16 round-to-nearest-even (finite values only)
__device__ inline unsigned short f2bf(float f) {
    unsigned u = __float_as_uint(f);
    u += 0x7FFF + ((u >> 16) & 1);
    return (unsigned short)(u >> 16);
}

// ---------------------------------------------------------------------------
__global__ void k_zero_int(int* __restrict__ p, int n) {
    int stride = gridDim.x * blockDim.x;
    for (int i = blockIdx.x * blockDim.x + threadIdx.x; i < n; i += stride) p[i] = 0;
}

// ---------------------------------------------------------------------------
// master = concat(user_emb, item_emb); m16 = bf16(master)
// ---------------------------------------------------------------------------
__global__ void k_init(const float4* __restrict__ ue, const float4* __restrict__ ie,
                       float4* __restrict__ master, ushort4* __restrict__ m16,
                       int nUser4, int nTot4) {
    int stride = gridDim.x * blockDim.x;
    for (int i = blockIdx.x * blockDim.x + threadIdx.x; i < nTot4; i += stride) {
        float4 v = (i < nUser4) ? ue[i] : ie[i - nUser4];
        master[i] = v;
        ushort4 h;
        h.x = f2bf(v.x); h.y = f2bf(v.y); h.z = f2bf(v.z); h.w = f2bf(v.w);
        m16[i] = h;
    }
}

// ---------------------------------------------------------------------------
// CSR build step 1: per-row edge counts
// ---------------------------------------------------------------------------
__global__ void k_hist(const int* __restrict__ rows, int* __restrict__ counts, int E) {
    int e = blockIdx.x * blockDim.x + threadIdx.x;
    if (e < E) atomicAdd(&counts[rows[e]], 1);
}

// ---------------------------------------------------------------------------
// CSR build step 2a: per-1024-chunk partial sums
// ---------------------------------------------------------------------------
__global__ void k_scan_partial(const int* __restrict__ counts, int* __restrict__ partials, int N) {
    __shared__ int s[256];
    int t = threadIdx.x;
    int base = blockIdx.x * 1024 + t * 4;
    int sum = 0;
    #pragma unroll
    for (int k = 0; k < 4; ++k) { int i = base + k; if (i < N) sum += counts[i]; }
    s[t] = sum; __syncthreads();
    for (int off = 128; off; off >>= 1) { if (t < off) s[t] += s[t + off]; __syncthreads(); }
    if (t == 0) partials[blockIdx.x] = s[0];
}

// ---------------------------------------------------------------------------
// CSR build step 2b: exclusive scan of <=256 partials; also row_start[N]=E
// ---------------------------------------------------------------------------
__global__ void k_scan_block(const int* __restrict__ partials, int* __restrict__ blockoff,
                             int NB, int* __restrict__ row_start, int N, int E) {
    __shared__ int s[256];
    int t = threadIdx.x;
    int x = (t < NB) ? partials[t] : 0;
    s[t] = x; __syncthreads();
    for (int off = 1; off < 256; off <<= 1) {
        int v = (t >= off) ? s[t - off] : 0; __syncthreads();
        s[t] += v; __syncthreads();
    }
    if (t < NB) blockoff[t] = s[t] - x;   // exclusive
    if (t == 0) row_start[N] = E;
}

// ---------------------------------------------------------------------------
// CSR build step 2c: expand to row_start
// ---------------------------------------------------------------------------
__global__ void k_scan_expand(const int* __restrict__ counts, const int* __restrict__ blockoff,
                              int* __restrict__ row_start, int N) {
    __shared__ int s[256];
    int t = threadIdx.x, b = blockIdx.x;
    int base = b * 1024 + t * 4;
    int c0 = (base + 0 < N) ? counts[base + 0] : 0;
    int c1 = (base + 1 < N) ? counts[base + 1] : 0;
    int c2 = (base + 2 < N) ? counts[base + 2] : 0;
    int c3 = (base + 3 < N) ? counts[base + 3] : 0;
    int mySum = c0 + c1 + c2 + c3;
    s[t] = mySum; __syncthreads();
    for (int off = 1; off < 256; off <<= 1) {
        int v = (t >= off) ? s[t - off] : 0; __syncthreads();
        s[t] += v; __syncthreads();
    }
    int run = blockoff[b] + s[t] - mySum;
    if (base + 0 < N) { row_start[base + 0] = run; run += c0; }
    if (base + 1 < N) { row_start[base + 1] = run; run += c1; }
    if (base + 2 < N) { row_start[base + 2] = run; run += c2; }
    if (base + 3 < N) { row_start[base + 3] = run; run += c3; }
}

// ---------------------------------------------------------------------------
// bucket cursor init: bcur[b] = row_start[b*16]
// ---------------------------------------------------------------------------
__global__ void k_binit(const int* __restrict__ row_start, int* __restrict__ bcur,
                        int NBk, int N) {
    int i = blockIdx.x * blockDim.x + threadIdx.x;
    if (i < NBk) {
        int r = i << BSH; if (r > N) r = N;
        bcur[i] = row_start[r];
    }
}

// ---------------------------------------------------------------------------
// bucket append: tmp[p] = ((row&15)<<18 | col, val); p from bucket cursor.
// ~9375 hot write lines -> full write combining in L2.
// ---------------------------------------------------------------------------
__global__ void k_bucket(const int* __restrict__ rows, const int* __restrict__ cols,
                         const float* __restrict__ vals, int* __restrict__ bcur,
                         int2* __restrict__ tmp, int E) {
    int e = blockIdx.x * blockDim.x + threadIdx.x;
    if (e >= E) return;
    int r = rows[e];
    int p = atomicAdd(&bcur[r >> BSH], 1);
    int2 pr;
    pr.x = ((r & BMASK) << 18) | cols[e];   // col < 2^18 (N = 150000)
    pr.y = __float_as_int(vals[e]);
    tmp[p] = pr;
}

// ---------------------------------------------------------------------------
// finalize: one block per bucket; 16 LDS cursors; writes exact CSR slots in
// the bucket's contiguous region (write-friendly).
// ---------------------------------------------------------------------------
__global__ void k_finalize(const int2* __restrict__ tmp, const int* __restrict__ row_start,
                           int2* __restrict__ csr, int N) {
    __shared__ int cur[1 << BSH];
    int b = blockIdx.x;
    int t = threadIdx.x;
    int r0 = b << BSH;
    int r1 = r0 + (1 << BSH); if (r1 > N) r1 = N;
    if (r0 >= N) return;
    if (t < (1 << BSH)) {
        int r = r0 + t; if (r > N) r = N;
        cur[t] = row_start[r];
    }
    __syncthreads();
    int lo = row_start[r0], hi = row_start[r1];
    for (int e = lo + t; e < hi; e += blockDim.x) {
        int2 pr = tmp[e];
        int lr = pr.x >> 18;                       // 4-bit local row
        int p  = atomicAdd(&cur[lr], 1);           // LDS atomic
        csr[p] = make_int2(pr.x & 0x3FFFF, pr.y);
    }
}

// ---------------------------------------------------------------------------
// fused SpMM + growth-score update. One wave = 2 rows (one per 32-lane half),
// lane covers dims {2*sl, 2*sl+1} via ushort2 bf16 gather. One shfl pair +
// one VMEM load serve two edges.
// ---------------------------------------------------------------------------
__global__ void k_spmm(float* __restrict__ master,
                       const ushort* __restrict__ m16_in, ushort* __restrict__ m16_out,
                       const int2* __restrict__ csr,
                       const int* __restrict__ row_start, int N) {
    int gid  = blockIdx.x * blockDim.x + threadIdx.x;
    int w    = gid >> 6;
    int lane = gid & 63;
    int h    = lane >> 5;
    int sl   = lane & 31;
    int row  = 2 * w + h;
    if (2 * w >= N) return;
    if (row >= N) row = N - 1;            // N is even here; safety only
    int start = row_start[row], end = row_start[row + 1];

    float2 o = ((const float2*)(master + (size_t)row * D))[sl];
    float a0 = 0.f, a1 = 0.f;

    for (int j = 0;; j += 32) {
        int rem = end - start - j;
        int tk  = rem < 0 ? 0 : (rem > 32 ? 32 : rem);
        int u   = max(tk, __shfl(tk, lane ^ 32));   // max over both halves
        if (u == 0) break;
        int2 pr = (sl < tk) ? csr[start + j + sl] : make_int2(0, 0);
        for (int k = 0; k < u; ++k) {
            int cx = __shfl(pr.x, k, 32);           // per-half broadcast
            int vy = __shfl(pr.y, k, 32);
            float v = __int_as_float(vy);           // 0 for exhausted half
            unsigned pair = *(const unsigned*)(m16_in + (size_t)cx * D + 2 * sl);
            a0 = fmaf(v, __uint_as_float(pair << 16), a0);
            a1 = fmaf(v, __uint_as_float(pair & 0xFFFF0000u), a1);
        }
    }

    float d0 = o.x - a0 + 1e-6f;
    float d1 = o.y - a1 + 1e-6f;
    float s  = d0 * d0 + d1 * d1;
    #pragma unroll
    for (int off = 16; off; off >>= 1) s += __shfl_xor(s, off);  // within half
    float dn  = log1pf(sqrtf(s));
    float inv = 1.0f / (1.0f + dn);
    float o0 = (o.x + dn * a0) * inv;
    float o1 = (o.y + dn * a1) * inv;
    ((float2*)(master + (size_t)row * D))[sl] = make_float2(o0, o1);
    unsigned pk = ((unsigned)f2bf(o1) << 16) | (unsigned)f2bf(o0);
    *(unsigned*)(m16_out + (size_t)row * D + 2 * sl) = pk;
}

// ---------------------------------------------------------------------------
// gather snapshot rows for the queries; optionally add prev, scale.
// ---------------------------------------------------------------------------
__global__ void k_gather(const float* __restrict__ emb, const float* __restrict__ prev,
                         float* __restrict__ dst, const int* __restrict__ uid,
                         const int* __restrict__ iid, int nQ, int nU, float scale) {
    int gid  = blockIdx.x * blockDim.x + threadIdx.x;
    int r    = gid >> 6;
    int lane = gid & 63;
    if (r >= 2 * nQ) return;
    int src = (r < nQ) ? uid[r] : nU + iid[r - nQ];
    float v = emb[(size_t)src * D + lane];
    if (prev) v += prev[(size_t)r * D + lane];
    dst[(size_t)r * D + lane] = v * scale;
}

extern "C" void kernel_launch(void* const* d_in, const int* in_sizes, int n_in,
                              void* d_out, int out_size, void* d_ws, size_t ws_size,
                              hipStream_t stream) {
    const float* ue   = (const float*)d_in[0];
    const float* ie   = (const float*)d_in[1];
    const float* vals = (const float*)d_in[2];
    const int*   rows = (const int*)d_in[3];
    const int*   cols = (const int*)d_in[4];
    const int*   uid  = (const int*)d_in[5];
    const int*   iid  = (const int*)d_in[6];
    float*       out  = (float*)d_out;

    const int nU  = in_sizes[0] / D;
    const int nI  = in_sizes[1] / D;
    const int N   = nU + nI;
    const int E   = in_sizes[2];
    const int nQ  = in_sizes[5];
    const int NB  = (N + 1023) / 1024;
    const int NBk = (N + BMASK) >> BSH;

    // ---- workspace layout (16B aligned), ~97 MB ----
    char* p = (char*)d_ws;
    auto alloc = [&](size_t bytes) { char* r = p; p += (bytes + 15) & ~(size_t)15; return r; };
    float*  master    = (float*) alloc((size_t)N * D * 4);
    ushort* m16a      = (ushort*)alloc((size_t)N * D * 2);
    ushort* m16b      = (ushort*)alloc((size_t)N * D * 2);  // also aliases tmp (E*8 == N*D*2)
    int2*   csr_pair  = (int2*)  alloc((size_t)E * 8);
    int*    row_start = (int*)   alloc((size_t)(N + 1) * 4);
    int*    counts    = (int*)   alloc((size_t)N * 4);
    int*    bcur      = (int*)   alloc((size_t)NBk * 4);
    int*    partials  = (int*)   alloc((size_t)NB * 4);
    int*    blockoff  = (int*)   alloc((size_t)NB * 4);
    float*  outacc    = (float*) alloc((size_t)2 * nQ * D * 4);
    int2*   tmp       = (int2*)m16b;   // dead until spmm-1 output

    const int eBlocks    = (E + 255) / 256;
    const int spmmBlocks = (((N + 1) / 2) * 64 + 255) / 256;
    const int gatBlocks  = (2 * nQ * 64 + 255) / 256;

    // ---- init + CSR build (bucket sort; reused by all 3 layers) ----
    k_zero_int<<<256, 256, 0, stream>>>(counts, N);
    k_init<<<2048, 256, 0, stream>>>((const float4*)ue, (const float4*)ie,
                                     (float4*)master, (ushort4*)m16a,
                                     in_sizes[0] / 4, N * D / 4);
    k_hist<<<eBlocks, 256, 0, stream>>>(rows, counts, E);
    k_scan_partial<<<NB, 256, 0, stream>>>(counts, partials, N);
    k_scan_block<<<1, 256, 0, stream>>>(partials, blockoff, NB, row_start, N, E);
    k_scan_expand<<<NB, 256, 0, stream>>>(counts, blockoff, row_start, N);
    k_binit<<<(NBk + 255) / 256, 256, 0, stream>>>(row_start, bcur, NBk, N);
    k_bucket<<<eBlocks, 256, 0, stream>>>(rows, cols, vals, bcur, tmp, E);
    k_finalize<<<NBk, 256, 0, stream>>>(tmp, row_start, csr_pair, N);

    // ---- snapshot 0 ----
    k_gather<<<gatBlocks, 256, 0, stream>>>(master, nullptr, outacc, uid, iid, nQ, nU, 1.0f);

    // ---- 3 fused layers (master in-place f32; bf16 mirror ping-pongs) ----
    k_spmm<<<spmmBlocks, 256, 0, stream>>>(master, m16a, m16b, csr_pair, row_start, N);
    k_gather<<<gatBlocks, 256, 0, stream>>>(master, outacc, outacc, uid, iid, nQ, nU, 1.0f);

    k_spmm<<<spmmBlocks, 256, 0, stream>>>(master, m16b, m16a, csr_pair, row_start, N);
    k_gather<<<gatBlocks, 256, 0, stream>>>(master, outacc, outacc, uid, iid, nQ, nU, 1.0f);

    k_spmm<<<spmmBlocks, 256, 0, stream>>>(master, m16a, m16b, csr_pair, row_start, N);
    k_gather<<<gatBlocks, 256, 0, stream>>>(master, outacc, out, uid, iid, nQ, nU, 0.25f);
}

// Round 9
// 620.554 us; speedup vs baseline: 10.1255x; 1.1001x over previous
//
#include <hip/hip_runtime.h>

#define D 64
#define CHUNK 2048
#define NTEAM 8

// f32 -> bf16 round-to-nearest-even (finite values only)
__device__ inline unsigned short f2bf(float f) {
    unsigned u = __float_as_uint(f);
    u += 0x7FFF + ((u >> 16) & 1);
    return (unsigned short)(u >> 16);
}

// ---------------------------------------------------------------------------
__global__ void k_zero_int(int* __restrict__ p, int n) {
    int stride = gridDim.x * blockDim.x;
    for (int i = blockIdx.x * blockDim.x + threadIdx.x; i < n; i += stride) p[i] = 0;
}

// ---------------------------------------------------------------------------
// master = concat(user_emb, item_emb); m16 = bf16(master)
// ---------------------------------------------------------------------------
__global__ void k_init(const float4* __restrict__ ue, const float4* __restrict__ ie,
                       float4* __restrict__ master, ushort4* __restrict__ m16,
                       int nUser4, int nTot4) {
    int stride = gridDim.x * blockDim.x;
    for (int i = blockIdx.x * blockDim.x + threadIdx.x; i < nTot4; i += stride) {
        float4 v = (i < nUser4) ? ue[i] : ie[i - nUser4];
        master[i] = v;
        ushort4 h;
        h.x = f2bf(v.x); h.y = f2bf(v.y); h.z = f2bf(v.z); h.w = f2bf(v.w);
        m16[i] = h;
    }
}

// ---------------------------------------------------------------------------
// CSR build step 1: per-row edge counts
// ---------------------------------------------------------------------------
__global__ void k_hist(const int* __restrict__ rows, int* __restrict__ counts, int E) {
    int e = blockIdx.x * blockDim.x + threadIdx.x;
    if (e < E) atomicAdd(&counts[rows[e]], 1);
}

// ---------------------------------------------------------------------------
// CSR build step 2a: per-1024-chunk partial sums
// ---------------------------------------------------------------------------
__global__ void k_scan_partial(const int* __restrict__ counts, int* __restrict__ partials, int N) {
    __shared__ int s[256];
    int t = threadIdx.x;
    int base = blockIdx.x * 1024 + t * 4;
    int sum = 0;
    #pragma unroll
    for (int k = 0; k < 4; ++k) { int i = base + k; if (i < N) sum += counts[i]; }
    s[t] = sum; __syncthreads();
    for (int off = 128; off; off >>= 1) { if (t < off) s[t] += s[t + off]; __syncthreads(); }
    if (t == 0) partials[blockIdx.x] = s[0];
}

// ---------------------------------------------------------------------------
// CSR build step 2b: exclusive scan of <=256 partials; also row_start[N]=E
// ---------------------------------------------------------------------------
__global__ void k_scan_block(const int* __restrict__ partials, int* __restrict__ blockoff,
                             int NB, int* __restrict__ row_start, int N, int E) {
    __shared__ int s[256];
    int t = threadIdx.x;
    int x = (t < NB) ? partials[t] : 0;
    s[t] = x; __syncthreads();
    for (int off = 1; off < 256; off <<= 1) {
        int v = (t >= off) ? s[t - off] : 0; __syncthreads();
        s[t] += v; __syncthreads();
    }
    if (t < NB) blockoff[t] = s[t] - x;   // exclusive
    if (t == 0) row_start[N] = E;
}

// ---------------------------------------------------------------------------
// CSR build step 2c: expand to row_start + cursor
// ---------------------------------------------------------------------------
__global__ void k_scan_expand(const int* __restrict__ counts, const int* __restrict__ blockoff,
                              int* __restrict__ row_start, int* __restrict__ cursor, int N) {
    __shared__ int s[256];
    int t = threadIdx.x, b = blockIdx.x;
    int base = b * 1024 + t * 4;
    int c0 = (base + 0 < N) ? counts[base + 0] : 0;
    int c1 = (base + 1 < N) ? counts[base + 1] : 0;
    int c2 = (base + 2 < N) ? counts[base + 2] : 0;
    int c3 = (base + 3 < N) ? counts[base + 3] : 0;
    int mySum = c0 + c1 + c2 + c3;
    s[t] = mySum; __syncthreads();
    for (int off = 1; off < 256; off <<= 1) {
        int v = (t >= off) ? s[t - off] : 0; __syncthreads();
        s[t] += v; __syncthreads();
    }
    int run = blockoff[b] + s[t] - mySum;
    if (base + 0 < N) { row_start[base + 0] = run; cursor[base + 0] = run; run += c0; }
    if (base + 1 < N) { row_start[base + 1] = run; cursor[base + 1] = run; run += c1; }
    if (base + 2 < N) { row_start[base + 2] = run; cursor[base + 2] = run; run += c2; }
    if (base + 3 < N) { row_start[base + 3] = run; cursor[base + 3] = run; run += c3; }
}

// ---------------------------------------------------------------------------
// CSR fill, XCD-partitioned: team = blockIdx&7 (round-robin XCD heuristic;
// correctness independent of mapping). Each team scans ALL edges via an
// atomic chunk counter and fills only its contiguous row range, so each
// team's 2.4 MB CSR window stays resident in ONE XCD's L2 until lines are
// fully written (kills the 7x cross-XCD write amplification seen in
// k_bucket: 140 MB -> ~25 MB).
// ---------------------------------------------------------------------------
__global__ void k_fill_xcd(const int* __restrict__ rows, const int* __restrict__ cols,
                           const float* __restrict__ vals, int* __restrict__ cursor,
                           int* __restrict__ work, int2* __restrict__ csr,
                           int E, int rowsPerTeam, int N) {
    int team = blockIdx.x & (NTEAM - 1);
    int lo = team * rowsPerTeam;
    int hi = lo + rowsPerTeam; if (hi > N) hi = N;
    __shared__ int s_base;
    for (;;) {
        if (threadIdx.x == 0) s_base = atomicAdd(&work[team], CHUNK);
        __syncthreads();
        int base = s_base;
        __syncthreads();
        if (base >= E) break;
        int top = base + CHUNK; if (top > E) top = E;
        for (int e = base + threadIdx.x; e < top; e += 256) {
            int r = rows[e];
            if (r >= lo && r < hi) {
                int p = atomicAdd(&cursor[r], 1);
                csr[p] = make_int2(cols[e], __float_as_int(vals[e]));
            }
        }
    }
}

// ---------------------------------------------------------------------------
// fused SpMM + growth-score update. One wave = 4 rows (16 lanes each),
// lane covers dims {4*sl .. 4*sl+3} via one uint2 bf16 gather. One shfl pair
// + one 8B load serve four dims x shared by the 16-lane group.
// ---------------------------------------------------------------------------
__global__ void k_spmm(float* __restrict__ master,
                       const ushort* __restrict__ m16_in, ushort* __restrict__ m16_out,
                       const int2* __restrict__ csr,
                       const int* __restrict__ row_start, int N) {
    int gid  = blockIdx.x * blockDim.x + threadIdx.x;
    int w    = gid >> 6;
    int lane = gid & 63;
    int q    = lane >> 4;          // quarter 0..3
    int sl   = lane & 15;          // sub-lane within quarter
    int row  = 4 * w + q;
    if (4 * w >= N) return;
    if (row >= N) row = N - 1;     // benign duplicate (identical bytes written)
    int start = row_start[row];
    int deg   = row_start[row + 1] - start;

    float4 o = ((const float4*)(master + (size_t)row * D))[sl];
    float a0 = 0.f, a1 = 0.f, a2 = 0.f, a3 = 0.f;

    for (int j = 0;; j += 16) {
        int tk = deg - j; tk = tk < 0 ? 0 : (tk > 16 ? 16 : tk);
        int m = max(tk, __shfl_xor(tk, 16));
        m = max(m, __shfl_xor(m, 32));
        if (m == 0) break;
        int2 pr = (sl < tk) ? csr[start + j + sl] : make_int2(0, 0);
        for (int k = 0; k < m; ++k) {
            int   cx = __shfl(pr.x, k, 16);           // per-quarter broadcast
            float v  = __int_as_float(__shfl(pr.y, k, 16)); // 0 when exhausted
            uint2 g = *(const uint2*)(m16_in + (size_t)cx * D + 4 * sl);
            a0 = fmaf(v, __uint_as_float(g.x << 16),          a0);
            a1 = fmaf(v, __uint_as_float(g.x & 0xFFFF0000u),  a1);
            a2 = fmaf(v, __uint_as_float(g.y << 16),          a2);
            a3 = fmaf(v, __uint_as_float(g.y & 0xFFFF0000u),  a3);
        }
    }

    float d0 = o.x - a0 + 1e-6f;
    float d1 = o.y - a1 + 1e-6f;
    float d2 = o.z - a2 + 1e-6f;
    float d3 = o.w - a3 + 1e-6f;
    float s = d0 * d0 + d1 * d1 + d2 * d2 + d3 * d3;
    #pragma unroll
    for (int off = 8; off; off >>= 1) s += __shfl_xor(s, off);  // 16-lane group
    float dn  = log1pf(sqrtf(s));
    float inv = 1.0f / (1.0f + dn);
    float o0 = (o.x + dn * a0) * inv;
    float o1 = (o.y + dn * a1) * inv;
    float o2 = (o.z + dn * a2) * inv;
    float o3 = (o.w + dn * a3) * inv;
    ((float4*)(master + (size_t)row * D))[sl] = make_float4(o0, o1, o2, o3);
    ushort4 pk;
    pk.x = f2bf(o0); pk.y = f2bf(o1); pk.z = f2bf(o2); pk.w = f2bf(o3);
    ((ushort4*)(m16_out + (size_t)row * D))[sl] = pk;
}

// ---------------------------------------------------------------------------
// gather snapshot rows for the queries; optionally add prev, scale.
// ---------------------------------------------------------------------------
__global__ void k_gather(const float* __restrict__ emb, const float* __restrict__ prev,
                         float* __restrict__ dst, const int* __restrict__ uid,
                         const int* __restrict__ iid, int nQ, int nU, float scale) {
    int gid  = blockIdx.x * blockDim.x + threadIdx.x;
    int r    = gid >> 6;
    int lane = gid & 63;
    if (r >= 2 * nQ) return;
    int src = (r < nQ) ? uid[r] : nU + iid[r - nQ];
    float v = emb[(size_t)src * D + lane];
    if (prev) v += prev[(size_t)r * D + lane];
    dst[(size_t)r * D + lane] = v * scale;
}

extern "C" void kernel_launch(void* const* d_in, const int* in_sizes, int n_in,
                              void* d_out, int out_size, void* d_ws, size_t ws_size,
                              hipStream_t stream) {
    const float* ue   = (const float*)d_in[0];
    const float* ie   = (const float*)d_in[1];
    const float* vals = (const float*)d_in[2];
    const int*   rows = (const int*)d_in[3];
    const int*   cols = (const int*)d_in[4];
    const int*   uid  = (const int*)d_in[5];
    const int*   iid  = (const int*)d_in[6];
    float*       out  = (float*)d_out;

    const int nU  = in_sizes[0] / D;
    const int nI  = in_sizes[1] / D;
    const int N   = nU + nI;
    const int E   = in_sizes[2];
    const int nQ  = in_sizes[5];
    const int NB  = (N + 1023) / 1024;
    const int rowsPerTeam = (N + NTEAM - 1) / NTEAM;

    // ---- workspace layout (16B aligned), ~98 MB ----
    char* p = (char*)d_ws;
    auto alloc = [&](size_t bytes) { char* r = p; p += (bytes + 15) & ~(size_t)15; return r; };
    float*  master    = (float*) alloc((size_t)N * D * 4);
    ushort* m16a      = (ushort*)alloc((size_t)N * D * 2);
    ushort* m16b      = (ushort*)alloc((size_t)N * D * 2);
    int2*   csr_pair  = (int2*)  alloc((size_t)E * 8);
    int*    row_start = (int*)   alloc((size_t)(N + 1) * 4);
    int*    cursor    = (int*)   alloc((size_t)N * 4);
    int*    counts    = (int*)   alloc((size_t)(N + NTEAM) * 4);  // + work[8] appended
    int*    work      = counts + N;
    int*    partials  = (int*)   alloc((size_t)NB * 4);
    int*    blockoff  = (int*)   alloc((size_t)NB * 4);
    float*  outacc    = (float*) alloc((size_t)2 * nQ * D * 4);

    const int eBlocks    = (E + 255) / 256;
    const int spmmBlocks = (((N + 3) / 4) * 64 + 255) / 256;
    const int gatBlocks  = (2 * nQ * 64 + 255) / 256;

    // ---- init + CSR build (reused by all 3 layers) ----
    k_zero_int<<<256, 256, 0, stream>>>(counts, N + NTEAM);
    k_init<<<2048, 256, 0, stream>>>((const float4*)ue, (const float4*)ie,
                                     (float4*)master, (ushort4*)m16a,
                                     in_sizes[0] / 4, N * D / 4);
    k_hist<<<eBlocks, 256, 0, stream>>>(rows, counts, E);
    k_scan_partial<<<NB, 256, 0, stream>>>(counts, partials, N);
    k_scan_block<<<1, 256, 0, stream>>>(partials, blockoff, NB, row_start, N, E);
    k_scan_expand<<<NB, 256, 0, stream>>>(counts, blockoff, row_start, cursor, N);
    k_fill_xcd<<<2048, 256, 0, stream>>>(rows, cols, vals, cursor, work, csr_pair,
                                         E, rowsPerTeam, N);

    // ---- snapshot 0 ----
    k_gather<<<gatBlocks, 256, 0, stream>>>(master, nullptr, outacc, uid, iid, nQ, nU, 1.0f);

    // ---- 3 fused layers (master in-place f32; bf16 mirror ping-pongs) ----
    k_spmm<<<spmmBlocks, 256, 0, stream>>>(master, m16a, m16b, csr_pair, row_start, N);
    k_gather<<<gatBlocks, 256, 0, stream>>>(master, outacc, outacc, uid, iid, nQ, nU, 1.0f);

    k_spmm<<<spmmBlocks, 256, 0, stream>>>(master, m16b, m16a, csr_pair, row_start, N);
    k_gather<<<gatBlocks, 256, 0, stream>>>(master, outacc, outacc, uid, iid, nQ, nU, 1.0f);

    k_spmm<<<spmmBlocks, 256, 0, stream>>>(master, m16a, m16b, csr_pair, row_start, N);
    k_gather<<<gatBlocks, 256, 0, stream>>>(master, outacc, out, uid, iid, nQ, nU, 0.25f);
}

// Round 12
// 473.250 us; speedup vs baseline: 13.2772x; 1.3113x over previous
//
#include <hip/hip_runtime.h>

#define D 64
#define BSH 10                    // rows per bucket = 1024
#define NBUCK_MAX 256             // N=150000 -> 147 buckets
#define TILE 4096                 // edges per Phase-A block
#define KPT (TILE / 256)          // 16 edges per thread

// f32 <-> bf16 (round-to-nearest-even; finite values only)
__device__ inline unsigned short f2bf(float f) {
    unsigned u = __float_as_uint(f);
    u += 0x7FFF + ((u >> 16) & 1);
    return (unsigned short)(u >> 16);
}
__device__ inline float bf2f(unsigned short h) {
    return __uint_as_float((unsigned)h << 16);
}

// ---------------------------------------------------------------------------
__global__ void k_zero_int(int* __restrict__ p, int n) {
    int stride = gridDim.x * blockDim.x;
    for (int i = blockIdx.x * blockDim.x + threadIdx.x; i < n; i += stride) p[i] = 0;
}

// ---------------------------------------------------------------------------
// m16 = bf16(concat(user_emb, item_emb))   (state is bf16-only now)
// ---------------------------------------------------------------------------
__global__ void k_init(const float4* __restrict__ ue, const float4* __restrict__ ie,
                       ushort4* __restrict__ m16, int nUser4, int nTot4) {
    int stride = gridDim.x * blockDim.x;
    for (int i = blockIdx.x * blockDim.x + threadIdx.x; i < nTot4; i += stride) {
        float4 v = (i < nUser4) ? ue[i] : ie[i - nUser4];
        ushort4 h;
        h.x = f2bf(v.x); h.y = f2bf(v.y); h.z = f2bf(v.z); h.w = f2bf(v.w);
        m16[i] = h;
    }
}

// ---------------------------------------------------------------------------
// CSR build step 1: per-row edge counts
// ---------------------------------------------------------------------------
__global__ void k_hist(const int* __restrict__ rows, int* __restrict__ counts, int E) {
    int e = blockIdx.x * blockDim.x + threadIdx.x;
    if (e < E) atomicAdd(&counts[rows[e]], 1);
}

// ---------------------------------------------------------------------------
// CSR build step 2a: per-1024-chunk partial sums
// ---------------------------------------------------------------------------
__global__ void k_scan_partial(const int* __restrict__ counts, int* __restrict__ partials, int N) {
    __shared__ int s[256];
    int t = threadIdx.x;
    int base = blockIdx.x * 1024 + t * 4;
    int sum = 0;
    #pragma unroll
    for (int k = 0; k < 4; ++k) { int i = base + k; if (i < N) sum += counts[i]; }
    s[t] = sum; __syncthreads();
    for (int off = 128; off; off >>= 1) { if (t < off) s[t] += s[t + off]; __syncthreads(); }
    if (t == 0) partials[blockIdx.x] = s[0];
}

// ---------------------------------------------------------------------------
// CSR build step 2b: exclusive scan of <=256 partials; also row_start[N]=E
// ---------------------------------------------------------------------------
__global__ void k_scan_block(const int* __restrict__ partials, int* __restrict__ blockoff,
                             int NB, int* __restrict__ row_start, int N, int E) {
    __shared__ int s[256];
    int t = threadIdx.x;
    int x = (t < NB) ? partials[t] : 0;
    s[t] = x; __syncthreads();
    for (int off = 1; off < 256; off <<= 1) {
        int v = (t >= off) ? s[t - off] : 0; __syncthreads();
        s[t] += v; __syncthreads();
    }
    if (t < NB) blockoff[t] = s[t] - x;   // exclusive
    if (t == 0) row_start[N] = E;
}

// ---------------------------------------------------------------------------
// CSR build step 2c: expand to row_start
// ---------------------------------------------------------------------------
__global__ void k_scan_expand(const int* __restrict__ counts, const int* __restrict__ blockoff,
                              int* __restrict__ row_start, int N) {
    __shared__ int s[256];
    int t = threadIdx.x, b = blockIdx.x;
    int base = b * 1024 + t * 4;
    int c0 = (base + 0 < N) ? counts[base + 0] : 0;
    int c1 = (base + 1 < N) ? counts[base + 1] : 0;
    int c2 = (base + 2 < N) ? counts[base + 2] : 0;
    int c3 = (base + 3 < N) ? counts[base + 3] : 0;
    int mySum = c0 + c1 + c2 + c3;
    s[t] = mySum; __syncthreads();
    for (int off = 1; off < 256; off <<= 1) {
        int v = (t >= off) ? s[t - off] : 0; __syncthreads();
        s[t] += v; __syncthreads();
    }
    int run = blockoff[b] + s[t] - mySum;
    if (base + 0 < N) { row_start[base + 0] = run; run += c0; }
    if (base + 1 < N) { row_start[base + 1] = run; run += c1; }
    if (base + 2 < N) { row_start[base + 2] = run; run += c2; }
    if (base + 3 < N) { row_start[base + 3] = run; run += c3; }
}

// ---------------------------------------------------------------------------
// seed Phase-A bucket cursors: gcur[b] = row_start[b << BSH]
// ---------------------------------------------------------------------------
__global__ void k_binit(const int* __restrict__ row_start, int* __restrict__ gcur,
                        int nbuck, int N) {
    int i = blockIdx.x * blockDim.x + threadIdx.x;
    if (i < nbuck) {
        int r = i << BSH; if (r > N) r = N;
        gcur[i] = row_start[r];
    }
}

// ---------------------------------------------------------------------------
// Phase A: tile 4096 edges -> LDS-rank into 147 buckets -> LDS compaction ->
// contiguous ~224B bucket-runs streamed to tmp. (Round-9 lesson: scattered
// 8B stores NEVER combine in L2; contiguity must exist before the store.)
// ---------------------------------------------------------------------------
__global__ void k_bucket2(const int* __restrict__ rows, const int* __restrict__ cols,
                          const float* __restrict__ vals, int* __restrict__ gcur,
                          int2* __restrict__ tmp, int E, int nbuck) {
    __shared__ int2 lpair[TILE];
    __shared__ int  ldst[TILE];
    __shared__ int  cnt[NBUCK_MAX];
    __shared__ int  base[NBUCK_MAX];
    __shared__ int  ofs[NBUCK_MAX];
    __shared__ int  ss[256];
    int tid = threadIdx.x;
    int tile0 = blockIdx.x * TILE;
    int tcount = (E - tile0 < TILE) ? (E - tile0) : TILE;

    for (int t = tid; t < nbuck; t += 256) cnt[t] = 0;
    __syncthreads();

    int  myb[KPT], myrank[KPT];
    int2 myp[KPT];
    #pragma unroll
    for (int k = 0; k < KPT; ++k) {
        int idx = k * 256 + tid;
        if (idx < tcount) {
            int e = tile0 + idx;
            int r = rows[e];
            int b = r >> BSH;
            myb[k]    = b;
            myrank[k] = atomicAdd(&cnt[b], 1);
            myp[k]    = make_int2(((r & ((1 << BSH) - 1)) << 18) | cols[e],
                                  __float_as_int(vals[e]));
        }
    }
    __syncthreads();

    // exclusive scan of cnt (nbuck <= 256) + grab global bucket space
    int v = (tid < nbuck) ? cnt[tid] : 0;
    ss[tid] = v; __syncthreads();
    for (int off = 1; off < 256; off <<= 1) {
        int y = (tid >= off) ? ss[tid - off] : 0; __syncthreads();
        ss[tid] += y; __syncthreads();
    }
    if (tid < nbuck) {
        ofs[tid] = ss[tid] - v;
        if (v > 0) base[tid] = atomicAdd(&gcur[tid], v);
    }
    __syncthreads();

    // compact into bucket-sorted LDS order + record global dests
    #pragma unroll
    for (int k = 0; k < KPT; ++k) {
        int idx = k * 256 + tid;
        if (idx < tcount) {
            int i = ofs[myb[k]] + myrank[k];
            lpair[i] = myp[k];
            ldst[i]  = base[myb[k]] + myrank[k];
        }
    }
    __syncthreads();

    // stream out: consecutive i -> mostly-consecutive dests (runs ~28 x 8B)
    for (int i = tid; i < tcount; i += 256)
        tmp[ldst[i]] = lpair[i];
}

// ---------------------------------------------------------------------------
// Phase B: one block per 1024-row bucket. Block-PRIVATE ~130KB CSR window
// (one CU -> one XCD -> lines combine). LDS row cursors, LDS atomics.
// ---------------------------------------------------------------------------
__global__ void k_finalize(const int2* __restrict__ tmp, const int* __restrict__ row_start,
                           int2* __restrict__ csr, int N) {
    __shared__ int cur[1 << BSH];
    int b = blockIdx.x, tid = threadIdx.x;
    int r0 = b << BSH;
    int r1 = r0 + (1 << BSH); if (r1 > N) r1 = N;
    int nr = r1 - r0;
    for (int t = tid; t < nr; t += 256) cur[t] = row_start[r0 + t];
    __syncthreads();
    int lo = row_start[r0];
    int hi = row_start[r1];
    for (int e = lo + tid; e < hi; e += 256) {
        int2 pr = tmp[e];
        int p = atomicAdd(&cur[pr.x >> 18], 1);       // LDS atomic
        csr[p] = make_int2(pr.x & 0x3FFFF, pr.y);
    }
}

// ---------------------------------------------------------------------------
// fused SpMM + growth-score update, bf16-only state. One wave = 4 rows
// (16 lanes each), lane covers 4 dims via one uint2 bf16 gather.
// ---------------------------------------------------------------------------
__global__ void k_spmm(const ushort* __restrict__ m16_in, ushort* __restrict__ m16_out,
                       const int2* __restrict__ csr,
                       const int* __restrict__ row_start, int N) {
    int gid  = blockIdx.x * blockDim.x + threadIdx.x;
    int w    = gid >> 6;
    int lane = gid & 63;
    int q    = lane >> 4;          // quarter 0..3
    int sl   = lane & 15;          // sub-lane within quarter
    int row  = 4 * w + q;
    if (4 * w >= N) return;
    if (row >= N) row = N - 1;     // benign duplicate (identical bytes written)
    int start = row_start[row];
    int deg   = row_start[row + 1] - start;

    uint2 og = *(const uint2*)(m16_in + (size_t)row * D + 4 * sl);
    float o0 = __uint_as_float(og.x << 16);
    float o1 = __uint_as_float(og.x & 0xFFFF0000u);
    float o2 = __uint_as_float(og.y << 16);
    float o3 = __uint_as_float(og.y & 0xFFFF0000u);
    float a0 = 0.f, a1 = 0.f, a2 = 0.f, a3 = 0.f;

    for (int j = 0;; j += 16) {
        int tk = deg - j; tk = tk < 0 ? 0 : (tk > 16 ? 16 : tk);
        int m = max(tk, __shfl_xor(tk, 16));
        m = max(m, __shfl_xor(m, 32));
        if (m == 0) break;
        int2 pr = (sl < tk) ? csr[start + j + sl] : make_int2(0, 0);
        for (int k = 0; k < m; ++k) {
            int   cx = __shfl(pr.x, k, 16);                 // per-quarter broadcast
            float vv = __int_as_float(__shfl(pr.y, k, 16)); // 0 when exhausted
            uint2 g = *(const uint2*)(m16_in + (size_t)cx * D + 4 * sl);
            a0 = fmaf(vv, __uint_as_float(g.x << 16),          a0);
            a1 = fmaf(vv, __uint_as_float(g.x & 0xFFFF0000u),  a1);
            a2 = fmaf(vv, __uint_as_float(g.y << 16),          a2);
            a3 = fmaf(vv, __uint_as_float(g.y & 0xFFFF0000u),  a3);
        }
    }

    float d0 = o0 - a0 + 1e-6f;
    float d1 = o1 - a1 + 1e-6f;
    float d2 = o2 - a2 + 1e-6f;
    float d3 = o3 - a3 + 1e-6f;
    float s = d0 * d0 + d1 * d1 + d2 * d2 + d3 * d3;
    #pragma unroll
    for (int off = 8; off; off >>= 1) s += __shfl_xor(s, off);  // 16-lane group
    float dn  = log1pf(sqrtf(s));
    float inv = 1.0f / (1.0f + dn);
    ushort4 pk;
    pk.x = f2bf((o0 + dn * a0) * inv);
    pk.y = f2bf((o1 + dn * a1) * inv);
    pk.z = f2bf((o2 + dn * a2) * inv);
    pk.w = f2bf((o3 + dn * a3) * inv);
    ((ushort4*)(m16_out + (size_t)row * D))[sl] = pk;
}

// ---------------------------------------------------------------------------
// gather snapshot rows (bf16 source) into f32 accumulator; optional prev+scale
// ---------------------------------------------------------------------------
__global__ void k_gather(const ushort* __restrict__ emb, const float* __restrict__ prev,
                         float* __restrict__ dst, const int* __restrict__ uid,
                         const int* __restrict__ iid, int nQ, int nU, float scale) {
    int gid  = blockIdx.x * blockDim.x + threadIdx.x;
    int r    = gid >> 6;
    int lane = gid & 63;
    if (r >= 2 * nQ) return;
    int src = (r < nQ) ? uid[r] : nU + iid[r - nQ];
    float v = bf2f(emb[(size_t)src * D + lane]);
    if (prev) v += prev[(size_t)r * D + lane];
    dst[(size_t)r * D + lane] = v * scale;
}

extern "C" void kernel_launch(void* const* d_in, const int* in_sizes, int n_in,
                              void* d_out, int out_size, void* d_ws, size_t ws_size,
                              hipStream_t stream) {
    const float* ue   = (const float*)d_in[0];
    const float* ie   = (const float*)d_in[1];
    const float* vals = (const float*)d_in[2];
    const int*   rows = (const int*)d_in[3];
    const int*   cols = (const int*)d_in[4];
    const int*   uid  = (const int*)d_in[5];
    const int*   iid  = (const int*)d_in[6];
    float*       out  = (float*)d_out;

    const int nU    = in_sizes[0] / D;
    const int nI    = in_sizes[1] / D;
    const int N     = nU + nI;
    const int E     = in_sizes[2];
    const int nQ    = in_sizes[5];
    const int NB    = (N + 1023) / 1024;
    const int nbuck = (N + (1 << BSH) - 1) >> BSH;     // 147 for N=150000

    // ---- workspace layout (16B aligned), ~61 MB ----
    char* p = (char*)d_ws;
    auto alloc = [&](size_t bytes) { char* r = p; p += (bytes + 15) & ~(size_t)15; return r; };
    ushort* m16a      = (ushort*)alloc((size_t)N * D * 2);
    ushort* m16b      = (ushort*)alloc((size_t)N * D * 2);  // aliases tmp during build
    int2*   csr_pair  = (int2*)  alloc((size_t)E * 8);
    int*    row_start = (int*)   alloc((size_t)(N + 1) * 4);
    int*    counts    = (int*)   alloc((size_t)(N + NBUCK_MAX) * 4);
    int*    gcur      = counts + N;
    int*    partials  = (int*)   alloc((size_t)NB * 4);
    int*    blockoff  = (int*)   alloc((size_t)NB * 4);
    float*  outacc    = (float*) alloc((size_t)2 * nQ * D * 4);
    int2*   tmp       = (int2*)m16b;   // E*8 == N*D*2 bytes; dead until spmm-1

    const int eBlocks    = (E + 255) / 256;
    const int aBlocks    = (E + TILE - 1) / TILE;      // 586
    const int spmmBlocks = (((N + 3) / 4) * 64 + 255) / 256;
    const int gatBlocks  = (2 * nQ * 64 + 255) / 256;

    // ---- init + CSR build (two-phase LDS-staged bucket sort) ----
    k_zero_int<<<256, 256, 0, stream>>>(counts, N);
    k_init<<<2048, 256, 0, stream>>>((const float4*)ue, (const float4*)ie,
                                     (ushort4*)m16a, in_sizes[0] / 4, N * D / 4);
    k_hist<<<eBlocks, 256, 0, stream>>>(rows, counts, E);
    k_scan_partial<<<NB, 256, 0, stream>>>(counts, partials, N);
    k_scan_block<<<1, 256, 0, stream>>>(partials, blockoff, NB, row_start, N, E);
    k_scan_expand<<<NB, 256, 0, stream>>>(counts, blockoff, row_start, N);
    k_binit<<<1, 256, 0, stream>>>(row_start, gcur, nbuck, N);
    k_bucket2<<<aBlocks, 256, 0, stream>>>(rows, cols, vals, gcur, tmp, E, nbuck);
    k_finalize<<<nbuck, 256, 0, stream>>>(tmp, row_start, csr_pair, N);

    // ---- snapshot 0 ----
    k_gather<<<gatBlocks, 256, 0, stream>>>(m16a, nullptr, outacc, uid, iid, nQ, nU, 1.0f);

    // ---- 3 fused layers (bf16 state ping-pongs) ----
    k_spmm<<<spmmBlocks, 256, 0, stream>>>(m16a, m16b, csr_pair, row_start, N);
    k_gather<<<gatBlocks, 256, 0, stream>>>(m16b, outacc, outacc, uid, iid, nQ, nU, 1.0f);

    k_spmm<<<spmmBlocks, 256, 0, stream>>>(m16b, m16a, csr_pair, row_start, N);
    k_gather<<<gatBlocks, 256, 0, stream>>>(m16a, outacc, outacc, uid, iid, nQ, nU, 1.0f);

    k_spmm<<<spmmBlocks, 256, 0, stream>>>(m16a, m16b, csr_pair, row_start, N);
    k_gather<<<gatBlocks, 256, 0, stream>>>(m16b, outacc, out, uid, iid, nQ, nU, 0.25f);
}

// Round 14
// 402.012 us; speedup vs baseline: 15.6299x; 1.1772x over previous
//
#include <hip/hip_runtime.h>

#define D 64
#define BSH 10                    // rows per bucket = 1024
#define NBUCK_MAX 256             // N=150000 -> 147 buckets
#define TILE 4096                 // edges per streaming block
#define KPT (TILE / 256)          // 16 edges per thread

// f32 <-> bf16 (round-to-nearest-even; finite values only)
__device__ inline unsigned short f2bf(float f) {
    unsigned u = __float_as_uint(f);
    u += 0x7FFF + ((u >> 16) & 1);
    return (unsigned short)(u >> 16);
}
__device__ inline float bf2f(unsigned short h) {
    return __uint_as_float((unsigned)h << 16);
}

// ---------------------------------------------------------------------------
__global__ void k_zero_int(int* __restrict__ p, int n) {
    int i = blockIdx.x * blockDim.x + threadIdx.x;
    if (i < n) p[i] = 0;
}

// ---------------------------------------------------------------------------
// m16 = bf16(concat(user_emb, item_emb))
// ---------------------------------------------------------------------------
__global__ void k_init(const float4* __restrict__ ue, const float4* __restrict__ ie,
                       ushort4* __restrict__ m16, int nUser4, int nTot4) {
    int stride = gridDim.x * blockDim.x;
    for (int i = blockIdx.x * blockDim.x + threadIdx.x; i < nTot4; i += stride) {
        float4 v = (i < nUser4) ? ue[i] : ie[i - nUser4];
        ushort4 h;
        h.x = f2bf(v.x); h.y = f2bf(v.y); h.z = f2bf(v.z); h.w = f2bf(v.w);
        m16[i] = h;
    }
}

// ---------------------------------------------------------------------------
// coarse bucket counts: per-block LDS hist of 147 buckets, then 147 global
// atomics per block (86K total vs k_hist's 2.4M — kills the 75MB WRITE).
// ---------------------------------------------------------------------------
__global__ void k_bcount(const int* __restrict__ rows, int* __restrict__ gtot,
                         int E, int nbuck) {
    __shared__ int h[NBUCK_MAX];
    int tid = threadIdx.x;
    for (int t = tid; t < nbuck; t += 256) h[t] = 0;
    __syncthreads();
    int tile0 = blockIdx.x * TILE;
    int top = tile0 + TILE; if (top > E) top = E;
    for (int e = tile0 + tid; e < top; e += 256)
        atomicAdd(&h[rows[e] >> BSH], 1);
    __syncthreads();
    for (int t = tid; t < nbuck; t += 256)
        if (h[t]) atomicAdd(&gtot[t], h[t]);
}

// ---------------------------------------------------------------------------
// scan 147 bucket totals -> bases; seed Phase-A cursors; sentinels.
// ---------------------------------------------------------------------------
__global__ void k_bscan(const int* __restrict__ gtot, int* __restrict__ gcur,
                        int* __restrict__ bbase, int* __restrict__ row_start,
                        int nbuck, int N, int E) {
    __shared__ int s[256];
    int t = threadIdx.x;
    int v = (t < nbuck) ? gtot[t] : 0;
    s[t] = v; __syncthreads();
    for (int off = 1; off < 256; off <<= 1) {
        int y = (t >= off) ? s[t - off] : 0; __syncthreads();
        s[t] += y; __syncthreads();
    }
    int base = s[t] - v;                       // exclusive
    if (t < nbuck) { gcur[t] = base; bbase[t] = base; }
    if (t == 0) { bbase[nbuck] = E; row_start[N] = E; }
}

// ---------------------------------------------------------------------------
// Phase A: tile 4096 edges -> LDS-rank into buckets -> LDS compaction ->
// contiguous bucket-runs streamed to tmp (contiguity created BEFORE store).
// ---------------------------------------------------------------------------
__global__ void k_bucket2(const int* __restrict__ rows, const int* __restrict__ cols,
                          const float* __restrict__ vals, int* __restrict__ gcur,
                          int2* __restrict__ tmp, int E, int nbuck) {
    __shared__ int2 lpair[TILE];
    __shared__ int  ldst[TILE];
    __shared__ int  cnt[NBUCK_MAX];
    __shared__ int  base[NBUCK_MAX];
    __shared__ int  ofs[NBUCK_MAX];
    __shared__ int  ss[256];
    int tid = threadIdx.x;
    int tile0 = blockIdx.x * TILE;
    int tcount = (E - tile0 < TILE) ? (E - tile0) : TILE;

    for (int t = tid; t < nbuck; t += 256) cnt[t] = 0;
    __syncthreads();

    int  myb[KPT], myrank[KPT];
    int2 myp[KPT];
    #pragma unroll
    for (int k = 0; k < KPT; ++k) {
        int idx = k * 256 + tid;
        if (idx < tcount) {
            int e = tile0 + idx;
            int r = rows[e];
            int b = r >> BSH;
            myb[k]    = b;
            myrank[k] = atomicAdd(&cnt[b], 1);
            myp[k]    = make_int2(((r & ((1 << BSH) - 1)) << 18) | cols[e],
                                  __float_as_int(vals[e]));
        }
    }
    __syncthreads();

    int v = (tid < nbuck) ? cnt[tid] : 0;
    ss[tid] = v; __syncthreads();
    for (int off = 1; off < 256; off <<= 1) {
        int y = (tid >= off) ? ss[tid - off] : 0; __syncthreads();
        ss[tid] += y; __syncthreads();
    }
    if (tid < nbuck) {
        ofs[tid] = ss[tid] - v;
        if (v > 0) base[tid] = atomicAdd(&gcur[tid], v);
    }
    __syncthreads();

    #pragma unroll
    for (int k = 0; k < KPT; ++k) {
        int idx = k * 256 + tid;
        if (idx < tcount) {
            int i = ofs[myb[k]] + myrank[k];
            lpair[i] = myp[k];
            ldst[i]  = base[myb[k]] + myrank[k];
        }
    }
    __syncthreads();

    for (int i = tid; i < tcount; i += 256)
        tmp[ldst[i]] = lpair[i];
}

// ---------------------------------------------------------------------------
// Phase B: one block per bucket. Pass 1: LDS hist of 1024 local rows.
// LDS scan -> row_start + cursors (no N-wide global hist/scan needed).
// Pass 2: place CSR entries (block-private 130KB window, L2-hot).
// ---------------------------------------------------------------------------
__global__ void k_finalize2(const int2* __restrict__ tmp, const int* __restrict__ bbase,
                            int* __restrict__ row_start, int2* __restrict__ csr, int N) {
    __shared__ int cnt[1 << BSH];     // counts -> cursors (reused)
    __shared__ int ps[256];
    int b = blockIdx.x, tid = threadIdx.x;
    int r0 = b << BSH;
    int lo = bbase[b], hi = bbase[b + 1];

    for (int t = tid; t < (1 << BSH); t += 256) cnt[t] = 0;
    __syncthreads();

    for (int e = lo + tid; e < hi; e += 256)
        atomicAdd(&cnt[tmp[e].x >> 18], 1);
    __syncthreads();

    // exclusive scan of 1024 counts (each thread owns 4 consecutive)
    int c0 = cnt[tid * 4 + 0], c1 = cnt[tid * 4 + 1];
    int c2 = cnt[tid * 4 + 2], c3 = cnt[tid * 4 + 3];
    int mySum = c0 + c1 + c2 + c3;
    ps[tid] = mySum; __syncthreads();
    for (int off = 1; off < 256; off <<= 1) {
        int y = (tid >= off) ? ps[tid - off] : 0; __syncthreads();
        ps[tid] += y; __syncthreads();
    }
    int run = lo + ps[tid] - mySum;
    int rs0 = run, rs1 = rs0 + c0, rs2 = rs1 + c1, rs3 = rs2 + c2;
    __syncthreads();                 // done reading cnt as counts
    cnt[tid * 4 + 0] = rs0; cnt[tid * 4 + 1] = rs1;
    cnt[tid * 4 + 2] = rs2; cnt[tid * 4 + 3] = rs3;
    int r = r0 + tid * 4;
    if (r + 0 < N) row_start[r + 0] = rs0;
    if (r + 1 < N) row_start[r + 1] = rs1;
    if (r + 2 < N) row_start[r + 2] = rs2;
    if (r + 3 < N) row_start[r + 3] = rs3;
    __syncthreads();

    for (int e = lo + tid; e < hi; e += 256) {
        int2 pr = tmp[e];
        int p = atomicAdd(&cnt[pr.x >> 18], 1);   // LDS atomic
        csr[p] = make_int2(pr.x & 0x3FFFF, pr.y);
    }
}

// ---------------------------------------------------------------------------
// fused SpMM + growth-score update, bf16-only state. One wave = 4 rows
// (16 lanes each), lane covers 4 dims via one uint2 bf16 gather.
// ---------------------------------------------------------------------------
__global__ void k_spmm(const ushort* __restrict__ m16_in, ushort* __restrict__ m16_out,
                       const int2* __restrict__ csr,
                       const int* __restrict__ row_start, int N) {
    int gid  = blockIdx.x * blockDim.x + threadIdx.x;
    int w    = gid >> 6;
    int lane = gid & 63;
    int q    = lane >> 4;          // quarter 0..3
    int sl   = lane & 15;          // sub-lane within quarter
    int row  = 4 * w + q;
    if (4 * w >= N) return;
    if (row >= N) row = N - 1;     // benign duplicate (identical bytes written)
    int start = row_start[row];
    int deg   = row_start[row + 1] - start;

    uint2 og = *(const uint2*)(m16_in + (size_t)row * D + 4 * sl);
    float o0 = __uint_as_float(og.x << 16);
    float o1 = __uint_as_float(og.x & 0xFFFF0000u);
    float o2 = __uint_as_float(og.y << 16);
    float o3 = __uint_as_float(og.y & 0xFFFF0000u);
    float a0 = 0.f, a1 = 0.f, a2 = 0.f, a3 = 0.f;

    for (int j = 0;; j += 16) {
        int tk = deg - j; tk = tk < 0 ? 0 : (tk > 16 ? 16 : tk);
        int m = max(tk, __shfl_xor(tk, 16));
        m = max(m, __shfl_xor(m, 32));
        if (m == 0) break;
        int2 pr = (sl < tk) ? csr[start + j + sl] : make_int2(0, 0);
        for (int k = 0; k < m; ++k) {
            int   cx = __shfl(pr.x, k, 16);                 // per-quarter broadcast
            float vv = __int_as_float(__shfl(pr.y, k, 16)); // 0 when exhausted
            uint2 g = *(const uint2*)(m16_in + (size_t)cx * D + 4 * sl);
            a0 = fmaf(vv, __uint_as_float(g.x << 16),          a0);
            a1 = fmaf(vv, __uint_as_float(g.x & 0xFFFF0000u),  a1);
            a2 = fmaf(vv, __uint_as_float(g.y << 16),          a2);
            a3 = fmaf(vv, __uint_as_float(g.y & 0xFFFF0000u),  a3);
        }
    }

    float d0 = o0 - a0 + 1e-6f;
    float d1 = o1 - a1 + 1e-6f;
    float d2 = o2 - a2 + 1e-6f;
    float d3 = o3 - a3 + 1e-6f;
    float s = d0 * d0 + d1 * d1 + d2 * d2 + d3 * d3;
    #pragma unroll
    for (int off = 8; off; off >>= 1) s += __shfl_xor(s, off);  // 16-lane group
    float dn  = log1pf(sqrtf(s));
    float inv = 1.0f / (1.0f + dn);
    ushort4 pk;
    pk.x = f2bf((o0 + dn * a0) * inv);
    pk.y = f2bf((o1 + dn * a1) * inv);
    pk.z = f2bf((o2 + dn * a2) * inv);
    pk.w = f2bf((o3 + dn * a3) * inv);
    ((ushort4*)(m16_out + (size_t)row * D))[sl] = pk;
}

// ---------------------------------------------------------------------------
// gather snapshot rows (bf16 source) into f32 accumulator; optional prev+scale
// ---------------------------------------------------------------------------
__global__ void k_gather(const ushort* __restrict__ emb, const float* __restrict__ prev,
                         float* __restrict__ dst, const int* __restrict__ uid,
                         const int* __restrict__ iid, int nQ, int nU, float scale) {
    int gid  = blockIdx.x * blockDim.x + threadIdx.x;
    int r    = gid >> 6;
    int lane = gid & 63;
    if (r >= 2 * nQ) return;
    int src = (r < nQ) ? uid[r] : nU + iid[r - nQ];
    float v = bf2f(emb[(size_t)src * D + lane]);
    if (prev) v += prev[(size_t)r * D + lane];
    dst[(size_t)r * D + lane] = v * scale;
}

extern "C" void kernel_launch(void* const* d_in, const int* in_sizes, int n_in,
                              void* d_out, int out_size, void* d_ws, size_t ws_size,
                              hipStream_t stream) {
    const float* ue   = (const float*)d_in[0];
    const float* ie   = (const float*)d_in[1];
    const float* vals = (const float*)d_in[2];
    const int*   rows = (const int*)d_in[3];
    const int*   cols = (const int*)d_in[4];
    const int*   uid  = (const int*)d_in[5];
    const int*   iid  = (const int*)d_in[6];
    float*       out  = (float*)d_out;

    const int nU    = in_sizes[0] / D;
    const int nI    = in_sizes[1] / D;
    const int N     = nU + nI;
    const int E     = in_sizes[2];
    const int nQ    = in_sizes[5];
    const int nbuck = (N + (1 << BSH) - 1) >> BSH;     // 147 for N=150000

    // ---- workspace layout (16B aligned), ~61 MB ----
    char* p = (char*)d_ws;
    auto alloc = [&](size_t bytes) { char* r = p; p += (bytes + 15) & ~(size_t)15; return r; };
    ushort* m16a      = (ushort*)alloc((size_t)N * D * 2);
    ushort* m16b      = (ushort*)alloc((size_t)N * D * 2);  // aliases tmp during build
    int2*   csr_pair  = (int2*)  alloc((size_t)E * 8);
    int*    row_start = (int*)   alloc((size_t)(N + 1) * 4);
    int*    gtot      = (int*)   alloc((size_t)NBUCK_MAX * 4);
    int*    gcur      = (int*)   alloc((size_t)NBUCK_MAX * 4);
    int*    bbase     = (int*)   alloc((size_t)(NBUCK_MAX + 1) * 4);
    float*  outacc    = (float*) alloc((size_t)2 * nQ * D * 4);
    int2*   tmp       = (int2*)m16b;   // E*8 == N*D*2 bytes; dead until spmm-1

    const int tBlocks    = (E + TILE - 1) / TILE;      // 586
    const int spmmBlocks = (((N + 3) / 4) * 64 + 255) / 256;
    const int gatBlocks  = (2 * nQ * 64 + 255) / 256;

    // ---- init + CSR build (bcount -> bscan -> bucket2 -> finalize2) ----
    k_zero_int<<<1, 256, 0, stream>>>(gtot, NBUCK_MAX);
    k_init<<<2048, 256, 0, stream>>>((const float4*)ue, (const float4*)ie,
                                     (ushort4*)m16a, in_sizes[0] / 4, N * D / 4);
    k_bcount<<<tBlocks, 256, 0, stream>>>(rows, gtot, E, nbuck);
    k_bscan<<<1, 256, 0, stream>>>(gtot, gcur, bbase, row_start, nbuck, N, E);
    k_bucket2<<<tBlocks, 256, 0, stream>>>(rows, cols, vals, gcur, tmp, E, nbuck);
    k_finalize2<<<nbuck, 256, 0, stream>>>(tmp, bbase, row_start, csr_pair, N);

    // ---- snapshot 0 ----
    k_gather<<<gatBlocks, 256, 0, stream>>>(m16a, nullptr, outacc, uid, iid, nQ, nU, 1.0f);

    // ---- 3 fused layers (bf16 state ping-pongs) ----
    k_spmm<<<spmmBlocks, 256, 0, stream>>>(m16a, m16b, csr_pair, row_start, N);
    k_gather<<<gatBlocks, 256, 0, stream>>>(m16b, outacc, outacc, uid, iid, nQ, nU, 1.0f);

    k_spmm<<<spmmBlocks, 256, 0, stream>>>(m16b, m16a, csr_pair, row_start, N);
    k_gather<<<gatBlocks, 256, 0, stream>>>(m16a, outacc, outacc, uid, iid, nQ, nU, 1.0f);

    k_spmm<<<spmmBlocks, 256, 0, stream>>>(m16a, m16b, csr_pair, row_start, N);
    k_gather<<<gatBlocks, 256, 0, stream>>>(m16b, outacc, out, uid, iid, nQ, nU, 0.25f);
}

// Round 15
// 357.983 us; speedup vs baseline: 17.5523x; 1.1230x over previous
//
#include <hip/hip_runtime.h>

#define D 64
#define BSH 10                    // rows per bucket = 1024
#define NBUCK_MAX 256             // N=150000 -> 147 buckets
#define TILE 4096                 // edges per streaming block
#define KPT (TILE / 256)          // 16 edges per thread

// f32 <-> bf16 (round-to-nearest-even; finite values only)
__device__ inline unsigned short f2bf(float f) {
    unsigned u = __float_as_uint(f);
    u += 0x7FFF + ((u >> 16) & 1);
    return (unsigned short)(u >> 16);
}
__device__ inline float bf2f(unsigned short h) {
    return __uint_as_float((unsigned)h << 16);
}

// ---------------------------------------------------------------------------
__global__ void k_zero_int(int* __restrict__ p, int n) {
    int i = blockIdx.x * blockDim.x + threadIdx.x;
    if (i < n) p[i] = 0;
}

// ---------------------------------------------------------------------------
// m16 = bf16(concat(user_emb, item_emb))
// ---------------------------------------------------------------------------
__global__ void k_init(const float4* __restrict__ ue, const float4* __restrict__ ie,
                       ushort4* __restrict__ m16, int nUser4, int nTot4) {
    int stride = gridDim.x * blockDim.x;
    for (int i = blockIdx.x * blockDim.x + threadIdx.x; i < nTot4; i += stride) {
        float4 v = (i < nUser4) ? ue[i] : ie[i - nUser4];
        ushort4 h;
        h.x = f2bf(v.x); h.y = f2bf(v.y); h.z = f2bf(v.z); h.w = f2bf(v.w);
        m16[i] = h;
    }
}

// ---------------------------------------------------------------------------
// coarse bucket counts: per-block LDS hist of 147 buckets, then 147 global
// atomics per block (86K total).
// ---------------------------------------------------------------------------
__global__ void k_bcount(const int* __restrict__ rows, int* __restrict__ gtot,
                         int E, int nbuck) {
    __shared__ int h[NBUCK_MAX];
    int tid = threadIdx.x;
    for (int t = tid; t < nbuck; t += 256) h[t] = 0;
    __syncthreads();
    int tile0 = blockIdx.x * TILE;
    int top = tile0 + TILE; if (top > E) top = E;
    for (int e = tile0 + tid; e < top; e += 256)
        atomicAdd(&h[rows[e] >> BSH], 1);
    __syncthreads();
    for (int t = tid; t < nbuck; t += 256)
        if (h[t]) atomicAdd(&gtot[t], h[t]);
}

// ---------------------------------------------------------------------------
// scan 147 bucket totals -> bases; seed Phase-A cursors; sentinels.
// ---------------------------------------------------------------------------
__global__ void k_bscan(const int* __restrict__ gtot, int* __restrict__ gcur,
                        int* __restrict__ bbase, int* __restrict__ row_start,
                        int nbuck, int N, int E) {
    __shared__ int s[256];
    int t = threadIdx.x;
    int v = (t < nbuck) ? gtot[t] : 0;
    s[t] = v; __syncthreads();
    for (int off = 1; off < 256; off <<= 1) {
        int y = (t >= off) ? s[t - off] : 0; __syncthreads();
        s[t] += y; __syncthreads();
    }
    int base = s[t] - v;                       // exclusive
    if (t < nbuck) { gcur[t] = base; bbase[t] = base; }
    if (t == 0) { bbase[nbuck] = E; row_start[N] = E; }
}

// ---------------------------------------------------------------------------
// Phase A: tile 4096 edges -> LDS-rank into buckets -> LDS compaction ->
// contiguous bucket-runs streamed to tmp (contiguity created BEFORE store).
// ---------------------------------------------------------------------------
__global__ void k_bucket2(const int* __restrict__ rows, const int* __restrict__ cols,
                          const float* __restrict__ vals, int* __restrict__ gcur,
                          int2* __restrict__ tmp, int E, int nbuck) {
    __shared__ int2 lpair[TILE];
    __shared__ int  ldst[TILE];
    __shared__ int  cnt[NBUCK_MAX];
    __shared__ int  base[NBUCK_MAX];
    __shared__ int  ofs[NBUCK_MAX];
    __shared__ int  ss[256];
    int tid = threadIdx.x;
    int tile0 = blockIdx.x * TILE;
    int tcount = (E - tile0 < TILE) ? (E - tile0) : TILE;

    for (int t = tid; t < nbuck; t += 256) cnt[t] = 0;
    __syncthreads();

    int  myb[KPT], myrank[KPT];
    int2 myp[KPT];
    #pragma unroll
    for (int k = 0; k < KPT; ++k) {
        int idx = k * 256 + tid;
        if (idx < tcount) {
            int e = tile0 + idx;
            int r = rows[e];
            int b = r >> BSH;
            myb[k]    = b;
            myrank[k] = atomicAdd(&cnt[b], 1);
            myp[k]    = make_int2(((r & ((1 << BSH) - 1)) << 18) | cols[e],
                                  __float_as_int(vals[e]));
        }
    }
    __syncthreads();

    int v = (tid < nbuck) ? cnt[tid] : 0;
    ss[tid] = v; __syncthreads();
    for (int off = 1; off < 256; off <<= 1) {
        int y = (tid >= off) ? ss[tid - off] : 0; __syncthreads();
        ss[tid] += y; __syncthreads();
    }
    if (tid < nbuck) {
        ofs[tid] = ss[tid] - v;
        if (v > 0) base[tid] = atomicAdd(&gcur[tid], v);
    }
    __syncthreads();

    #pragma unroll
    for (int k = 0; k < KPT; ++k) {
        int idx = k * 256 + tid;
        if (idx < tcount) {
            int i = ofs[myb[k]] + myrank[k];
            lpair[i] = myp[k];
            ldst[i]  = base[myb[k]] + myrank[k];
        }
    }
    __syncthreads();

    for (int i = tid; i < tcount; i += 256)
        tmp[ldst[i]] = lpair[i];
}

// ---------------------------------------------------------------------------
// Phase B: one block per bucket. Pass 1: LDS hist of 1024 local rows.
// LDS scan -> row_start + cursors. Pass 2: place CSR entries.
// ---------------------------------------------------------------------------
__global__ void k_finalize2(const int2* __restrict__ tmp, const int* __restrict__ bbase,
                            int* __restrict__ row_start, int2* __restrict__ csr, int N) {
    __shared__ int cnt[1 << BSH];     // counts -> cursors (reused)
    __shared__ int ps[256];
    int b = blockIdx.x, tid = threadIdx.x;
    int r0 = b << BSH;
    int lo = bbase[b], hi = bbase[b + 1];

    for (int t = tid; t < (1 << BSH); t += 256) cnt[t] = 0;
    __syncthreads();

    for (int e = lo + tid; e < hi; e += 256)
        atomicAdd(&cnt[tmp[e].x >> 18], 1);
    __syncthreads();

    // exclusive scan of 1024 counts (each thread owns 4 consecutive)
    int c0 = cnt[tid * 4 + 0], c1 = cnt[tid * 4 + 1];
    int c2 = cnt[tid * 4 + 2], c3 = cnt[tid * 4 + 3];
    int mySum = c0 + c1 + c2 + c3;
    ps[tid] = mySum; __syncthreads();
    for (int off = 1; off < 256; off <<= 1) {
        int y = (tid >= off) ? ps[tid - off] : 0; __syncthreads();
        ps[tid] += y; __syncthreads();
    }
    int run = lo + ps[tid] - mySum;
    int rs0 = run, rs1 = rs0 + c0, rs2 = rs1 + c1, rs3 = rs2 + c2;
    __syncthreads();                 // done reading cnt as counts
    cnt[tid * 4 + 0] = rs0; cnt[tid * 4 + 1] = rs1;
    cnt[tid * 4 + 2] = rs2; cnt[tid * 4 + 3] = rs3;
    int r = r0 + tid * 4;
    if (r + 0 < N) row_start[r + 0] = rs0;
    if (r + 1 < N) row_start[r + 1] = rs1;
    if (r + 2 < N) row_start[r + 2] = rs2;
    if (r + 3 < N) row_start[r + 3] = rs3;
    __syncthreads();

    for (int e = lo + tid; e < hi; e += 256) {
        int2 pr = tmp[e];
        int p = atomicAdd(&cnt[pr.x >> 18], 1);   // LDS atomic
        csr[p] = make_int2(pr.x & 0x3FFFF, pr.y);
    }
}

// ---------------------------------------------------------------------------
// fused SpMM + growth-score update, bf16-only state. One wave = 4 rows
// (16 lanes each). v3: broadcast via per-wave LDS stage (1 ds_read_b64/edge
// instead of 2 ds_bpermute + index setup); 32-bit gather offsets against the
// uniform m16_in base (no per-edge 64-bit address math).
// ---------------------------------------------------------------------------
__global__ void k_spmm(const ushort* __restrict__ m16_in, ushort* __restrict__ m16_out,
                       const int2* __restrict__ csr,
                       const int* __restrict__ row_start, int N) {
    __shared__ int2 stage[4][4][16];          // [wave][quarter][slot], 2 KB
    int tid  = threadIdx.x;
    int wv   = tid >> 6;
    int gid  = blockIdx.x * blockDim.x + tid;
    int w    = gid >> 6;
    int lane = gid & 63;
    int q    = lane >> 4;          // quarter 0..3
    int sl   = lane & 15;          // sub-lane within quarter
    int row  = 4 * w + q;
    if (4 * w >= N) return;
    if (row >= N) row = N - 1;     // benign duplicate (identical bytes written)
    int start = row_start[row];
    int deg   = row_start[row + 1] - start;

    const ushort* lanebase = m16_in + (sl << 2);      // + 4*sl (uniform-ish base)
    uint2 og = *(const uint2*)(lanebase + ((unsigned)row << 6));
    float o0 = __uint_as_float(og.x << 16);
    float o1 = __uint_as_float(og.x & 0xFFFF0000u);
    float o2 = __uint_as_float(og.y << 16);
    float o3 = __uint_as_float(og.y & 0xFFFF0000u);
    float a0 = 0.f, a1 = 0.f, a2 = 0.f, a3 = 0.f;

    for (int j = 0;; j += 16) {
        int tk = deg - j; tk = tk < 0 ? 0 : (tk > 16 ? 16 : tk);
        int m = max(tk, __shfl_xor(tk, 16));
        m = max(m, __shfl_xor(m, 32));
        if (m == 0) break;
        stage[wv][q][sl] = (sl < tk) ? csr[start + j + sl] : make_int2(0, 0);
        #pragma unroll 4
        for (int k = 0; k < m; ++k) {
            int2 e = stage[wv][q][k];                       // ds_read_b64
            float vv = __int_as_float(e.y);                 // 0 when padded
            uint2 g = *(const uint2*)(lanebase + ((unsigned)e.x << 6));
            a0 = fmaf(vv, __uint_as_float(g.x << 16),          a0);
            a1 = fmaf(vv, __uint_as_float(g.x & 0xFFFF0000u),  a1);
            a2 = fmaf(vv, __uint_as_float(g.y << 16),          a2);
            a3 = fmaf(vv, __uint_as_float(g.y & 0xFFFF0000u),  a3);
        }
    }

    float d0 = o0 - a0 + 1e-6f;
    float d1 = o1 - a1 + 1e-6f;
    float d2 = o2 - a2 + 1e-6f;
    float d3 = o3 - a3 + 1e-6f;
    float s = d0 * d0 + d1 * d1 + d2 * d2 + d3 * d3;
    #pragma unroll
    for (int off = 8; off; off >>= 1) s += __shfl_xor(s, off);  // 16-lane group
    float dn  = log1pf(sqrtf(s));
    float inv = 1.0f / (1.0f + dn);
    ushort4 pk;
    pk.x = f2bf((o0 + dn * a0) * inv);
    pk.y = f2bf((o1 + dn * a1) * inv);
    pk.z = f2bf((o2 + dn * a2) * inv);
    pk.w = f2bf((o3 + dn * a3) * inv);
    ((ushort4*)(m16_out + (size_t)row * D))[sl] = pk;
}

// ---------------------------------------------------------------------------
// gather snapshot rows (bf16 source) into f32 accumulator; optional prev+scale
// ---------------------------------------------------------------------------
__global__ void k_gather(const ushort* __restrict__ emb, const float* __restrict__ prev,
                         float* __restrict__ dst, const int* __restrict__ uid,
                         const int* __restrict__ iid, int nQ, int nU, float scale) {
    int gid  = blockIdx.x * blockDim.x + threadIdx.x;
    int r    = gid >> 6;
    int lane = gid & 63;
    if (r >= 2 * nQ) return;
    int src = (r < nQ) ? uid[r] : nU + iid[r - nQ];
    float v = bf2f(emb[(size_t)src * D + lane]);
    if (prev) v += prev[(size_t)r * D + lane];
    dst[(size_t)r * D + lane] = v * scale;
}

extern "C" void kernel_launch(void* const* d_in, const int* in_sizes, int n_in,
                              void* d_out, int out_size, void* d_ws, size_t ws_size,
                              hipStream_t stream) {
    const float* ue   = (const float*)d_in[0];
    const float* ie   = (const float*)d_in[1];
    const float* vals = (const float*)d_in[2];
    const int*   rows = (const int*)d_in[3];
    const int*   cols = (const int*)d_in[4];
    const int*   uid  = (const int*)d_in[5];
    const int*   iid  = (const int*)d_in[6];
    float*       out  = (float*)d_out;

    const int nU    = in_sizes[0] / D;
    const int nI    = in_sizes[1] / D;
    const int N     = nU + nI;
    const int E     = in_sizes[2];
    const int nQ    = in_sizes[5];
    const int nbuck = (N + (1 << BSH) - 1) >> BSH;     // 147 for N=150000

    // ---- workspace layout (16B aligned), ~61 MB ----
    char* p = (char*)d_ws;
    auto alloc = [&](size_t bytes) { char* r = p; p += (bytes + 15) & ~(size_t)15; return r; };
    ushort* m16a      = (ushort*)alloc((size_t)N * D * 2);
    ushort* m16b      = (ushort*)alloc((size_t)N * D * 2);  // aliases tmp during build
    int2*   csr_pair  = (int2*)  alloc((size_t)E * 8);
    int*    row_start = (int*)   alloc((size_t)(N + 1) * 4);
    int*    gtot      = (int*)   alloc((size_t)NBUCK_MAX * 4);
    int*    gcur      = (int*)   alloc((size_t)NBUCK_MAX * 4);
    int*    bbase     = (int*)   alloc((size_t)(NBUCK_MAX + 1) * 4);
    float*  outacc    = (float*) alloc((size_t)2 * nQ * D * 4);
    int2*   tmp       = (int2*)m16b;   // E*8 == N*D*2 bytes; dead until spmm-1

    const int tBlocks    = (E + TILE - 1) / TILE;      // 586
    const int spmmBlocks = (((N + 3) / 4) * 64 + 255) / 256;
    const int gatBlocks  = (2 * nQ * 64 + 255) / 256;

    // ---- init + CSR build (bcount -> bscan -> bucket2 -> finalize2) ----
    k_zero_int<<<1, 256, 0, stream>>>(gtot, NBUCK_MAX);
    k_init<<<2048, 256, 0, stream>>>((const float4*)ue, (const float4*)ie,
                                     (ushort4*)m16a, in_sizes[0] / 4, N * D / 4);
    k_bcount<<<tBlocks, 256, 0, stream>>>(rows, gtot, E, nbuck);
    k_bscan<<<1, 256, 0, stream>>>(gtot, gcur, bbase, row_start, nbuck, N, E);
    k_bucket2<<<tBlocks, 256, 0, stream>>>(rows, cols, vals, gcur, tmp, E, nbuck);
    k_finalize2<<<nbuck, 256, 0, stream>>>(tmp, bbase, row_start, csr_pair, N);

    // ---- snapshot 0 ----
    k_gather<<<gatBlocks, 256, 0, stream>>>(m16a, nullptr, outacc, uid, iid, nQ, nU, 1.0f);

    // ---- 3 fused layers (bf16 state ping-pongs) ----
    k_spmm<<<spmmBlocks, 256, 0, stream>>>(m16a, m16b, csr_pair, row_start, N);
    k_gather<<<gatBlocks, 256, 0, stream>>>(m16b, outacc, outacc, uid, iid, nQ, nU, 1.0f);

    k_spmm<<<spmmBlocks, 256, 0, stream>>>(m16b, m16a, csr_pair, row_start, N);
    k_gather<<<gatBlocks, 256, 0, stream>>>(m16a, outacc, outacc, uid, iid, nQ, nU, 1.0f);

    k_spmm<<<spmmBlocks, 256, 0, stream>>>(m16a, m16b, csr_pair, row_start, N);
    k_gather<<<gatBlocks, 256, 0, stream>>>(m16b, outacc, out, uid, iid, nQ, nU, 0.25f);
}